// Round 3
// baseline (439.181 us; speedup 1.0000x reference)
//
#include <hip/hip_runtime.h>

#define NN 20000
#define NE 300000

typedef unsigned short u16;
typedef unsigned int   u32;

typedef __bf16 bf16x8 __attribute__((ext_vector_type(8)));
typedef float  f32x4  __attribute__((ext_vector_type(4)));

__device__ __forceinline__ float b2f(u16 u){ u32 x = ((u32)u) << 16; return __builtin_bit_cast(float, x); }
__device__ __forceinline__ u16 f2b(float f){
    u32 x = __builtin_bit_cast(u32, f);
    u32 r = x + 0x7fffu + ((x >> 16) & 1u);
    return (u16)(r >> 16);
}

// ---------------- CSR build: bucket edges by col (target), store row (source) ----------------
__global__ void k_count(const int* __restrict__ key, int* __restrict__ deg){
    int e = blockIdx.x * 256 + threadIdx.x;
    if (e < NE){
        int c = key[e];
        if (c >= 0 && c < NN) atomicAdd(&deg[c], 1);
    }
}

__global__ void k_scan(const int* __restrict__ deg, int* __restrict__ offs, float* __restrict__ invd){
    __shared__ int part[1024];
    int t = threadIdx.x;
    int base = t * 20;
    int s = 0;
    for (int i = 0; i < 20; i++){ int idx = base + i; if (idx < NN) s += deg[idx]; }
    part[t] = s; __syncthreads();
    for (int d = 1; d < 1024; d <<= 1){
        int v = (t >= d) ? part[t - d] : 0;
        __syncthreads();
        part[t] += v;
        __syncthreads();
    }
    int run = part[t] - s;
    for (int i = 0; i < 20; i++){
        int idx = base + i;
        if (idx < NN){
            offs[idx] = run;
            int d0 = deg[idx];
            run += d0;
            invd[idx] = 1.0f / (float)(d0 > 0 ? d0 : 1);
        }
    }
    if (t == 1023) offs[NN] = part[1023];
}

__global__ void k_fill(const int* __restrict__ val, const int* __restrict__ key,
                       const int* __restrict__ offs, int* __restrict__ cur, int* __restrict__ srcs){
    int e = blockIdx.x * 256 + threadIdx.x;
    if (e < NE){
        int c = key[e];
        if (c >= 0 && c < NN){
            int slot = offs[c] + atomicAdd(&cur[c], 1);
            int r = val[e];
            srcs[slot] = (r >= 0 && r < NN) ? r : 0;
        }
    }
}

// ---------------- weight swizzle fp32 -> bf16 MFMA B-fragments ----------------
__global__ void k_swz_f32(const float* __restrict__ W, u16* __restrict__ dst, int N, int KT){
    int t = blockIdx.x * 256 + threadIdx.x;
    int j = t & 7, lane = (t >> 3) & 63, tile = t >> 9;
    int ktile = tile % KT, ntile = tile / KT;
    int k = ktile * 32 + ((lane >> 4) << 3) + j;
    int n = ntile * 16 + (lane & 15);
    dst[t] = f2b(W[k * N + n]);
}

__global__ void k_swz_pair_f32(const float* __restrict__ A, const float* __restrict__ B, u16* __restrict__ dst,
                               int halfK, int N, int KT){
    int t = blockIdx.x * 256 + threadIdx.x;
    int j = t & 7, lane = (t >> 3) & 63, tile = t >> 9;
    int ktile = tile % KT, ntile = tile / KT;
    int k = ktile * 32 + ((lane >> 4) << 3) + j;
    int n = ntile * 16 + (lane & 15);
    dst[t] = f2b((k < halfK) ? A[k * N + n] : B[(k - halfK) * N + n]);
}

// ---------------- SAGE layer 1 (din=3): fp32 math, bf16 output ----------------
__global__ void k_layer1(const float* __restrict__ x, const int* __restrict__ offs, const int* __restrict__ srcs,
                         const float* __restrict__ invd, const float* __restrict__ Wl, const float* __restrict__ bl,
                         const float* __restrict__ Wr, u16* __restrict__ h1){
    int node = blockIdx.x * 4 + (threadIdx.x >> 6);
    int lane = threadIdx.x & 63;
    int st = offs[node], en = offs[node + 1];
    float s0 = 0.f, s1 = 0.f, s2 = 0.f;
    for (int j = st + lane; j < en; j += 64){
        int s = srcs[j];
        s0 += x[s * 3 + 0]; s1 += x[s * 3 + 1]; s2 += x[s * 3 + 2];
    }
    #pragma unroll
    for (int d = 1; d < 64; d <<= 1){
        s0 += __shfl_xor(s0, d); s1 += __shfl_xor(s1, d); s2 += __shfl_xor(s2, d);
    }
    float inv = invd[node];
    float a0 = s0 * inv, a1 = s1 * inv, a2 = s2 * inv;
    float xi0 = x[node * 3 + 0], xi1 = x[node * 3 + 1], xi2 = x[node * 3 + 2];
    int f0 = lane * 4;
    ushort4 stv;
    u16* sp = (u16*)&stv;
    #pragma unroll
    for (int r = 0; r < 4; r++){
        int n = f0 + r;
        float o = a0 * Wl[n] + a1 * Wl[256 + n] + a2 * Wl[512 + n]
                + xi0 * Wr[n] + xi1 * Wr[256 + n] + xi2 * Wr[512 + n] + bl[n];
        sp[r] = f2b(o > 0.f ? o : 0.f);
    }
    *(ushort4*)(h1 + node * 256 + f0) = stv;
}

// ---------------- mean aggregation over CSR: 16B/lane, 2 rows in flight per wave ----------------
__global__ void k_aggr(const u16* __restrict__ hin, const int* __restrict__ offs, const int* __restrict__ srcs,
                       const float* __restrict__ invd, u16* __restrict__ aggr){
    int node = blockIdx.x * 4 + (threadIdx.x >> 6);
    int lane = threadIdx.x & 63;
    int st = offs[node], en = offs[node + 1];
    int half = lane >> 5;
    int c0 = (lane & 31) * 8;
    float a0=0.f,a1=0.f,a2=0.f,a3=0.f,a4=0.f,a5=0.f,a6=0.f,a7=0.f;
    for (int j = st + half; j < en; j += 2){
        int s = srcs[j];
        uint4 v = *(const uint4*)(hin + s * 256 + c0);
        a0 += b2f((u16)v.x); a1 += b2f((u16)(v.x >> 16));
        a2 += b2f((u16)v.y); a3 += b2f((u16)(v.y >> 16));
        a4 += b2f((u16)v.z); a5 += b2f((u16)(v.z >> 16));
        a6 += b2f((u16)v.w); a7 += b2f((u16)(v.w >> 16));
    }
    a0 += __shfl_xor(a0, 32); a1 += __shfl_xor(a1, 32);
    a2 += __shfl_xor(a2, 32); a3 += __shfl_xor(a3, 32);
    a4 += __shfl_xor(a4, 32); a5 += __shfl_xor(a5, 32);
    a6 += __shfl_xor(a6, 32); a7 += __shfl_xor(a7, 32);
    if (half == 0){
        float inv = invd[node];
        uint4 o;
        o.x = (u32)f2b(a0 * inv) | ((u32)f2b(a1 * inv) << 16);
        o.y = (u32)f2b(a2 * inv) | ((u32)f2b(a3 * inv) << 16);
        o.z = (u32)f2b(a4 * inv) | ((u32)f2b(a5 * inv) << 16);
        o.w = (u32)f2b(a6 * inv) | ((u32)f2b(a7 * inv) << 16);
        *(uint4*)(aggr + node * 256 + c0) = o;
    }
}

// ---------------- node dense layer: relu([aggr|hin] @ Bs + bias), MFMA, N-split grid ----------------
// grid (313, 2): block computes 64 rows x 128 cols. B staged through 8 KB LDS w/ register prefetch.
// (round-0 proven version; not the bottleneck)
__global__ __launch_bounds__(256) void k_gemm_node(const u16* __restrict__ aggr, const u16* __restrict__ hin,
    const u16* __restrict__ Bs, const float* __restrict__ bias, u16* __restrict__ out){
    __shared__ __align__(16) u16 ldsB[4096];   // 8 KB: one k32-chunk, 8 local ntiles
    int t = threadIdx.x, wave = t >> 6, lane = t & 63;
    int m0 = blockIdx.x * 64 + wave * 16;
    int nb = blockIdx.y * 8;                   // global ntile base (8 ntiles = 128 cols)
    int ml = lane & 15, g = lane >> 4;
    int arow = m0 + ml; if (arow > NN - 1) arow = NN - 1;
    const u16* pa = aggr + arow * 256;
    const u16* ph = hin  + arow * 256;

    int flat0 = t * 8, flat1 = (256 + t) * 8;
    int s0i = flat0 >> 9, o0 = flat0 & 511;    // local ntile 0..3
    int s1i = flat1 >> 9, o1 = flat1 & 511;    // local ntile 4..7
    uint4 p0 = *(const uint4*)(Bs + ((nb + s0i) * 16 + 0) * 512 + o0);
    uint4 p1 = *(const uint4*)(Bs + ((nb + s1i) * 16 + 0) * 512 + o1);

    f32x4 acc[8] = {};
    for (int k32 = 0; k32 < 16; k32++){
        __syncthreads();
        *(uint4*)(&ldsB[s0i * 512 + o0]) = p0;
        *(uint4*)(&ldsB[s1i * 512 + o1]) = p1;
        if (k32 < 15){
            p0 = *(const uint4*)(Bs + ((nb + s0i) * 16 + k32 + 1) * 512 + o0);
            p1 = *(const uint4*)(Bs + ((nb + s1i) * 16 + k32 + 1) * 512 + o1);
        }
        __syncthreads();
        const u16* asrc = (k32 < 8) ? (pa + k32 * 32) : (ph + (k32 - 8) * 32);
        bf16x8 af = __builtin_bit_cast(bf16x8, *(const uint4*)(asrc + g * 8));
        #pragma unroll
        for (int nt = 0; nt < 8; nt++){
            bf16x8 bfr = __builtin_bit_cast(bf16x8, *(const uint4*)(&ldsB[(nt * 64 + lane) * 8]));
            acc[nt] = __builtin_amdgcn_mfma_f32_16x16x32_bf16(af, bfr, acc[nt], 0, 0, 0);
        }
    }
    #pragma unroll
    for (int nt = 0; nt < 8; nt++){
        int n = (nb + nt) * 16 + ml;
        float bn = bias[n];
        #pragma unroll
        for (int r = 0; r < 4; r++){
            int rowg = m0 + g * 4 + r;
            if (rowg < NN){
                float v = acc[nt][r] + bn;
                out[rowg * 256 + n] = f2b(v > 0.f ? v : 0.f);
            }
        }
    }
}

// ---------------- bf16-MFMA edge MLP: 512 threads, 128 edges/block ----------------
// Wave = (mgrp 0..3, nhalf 0..1): M=32 edges per wave, N split across wave pairs.
// Each B-frag ds_read_b128 feeds 2 MFMAs; acc[2][8]=64 AGPR keeps total regs <=128
// -> 2 blocks/CU (4 waves/SIMD) at 80 KB LDS, with HALF the LDS read traffic of round 0.
__global__ __launch_bounds__(512, 4) void k_mlp_bf16(const u16* __restrict__ h3b, const int* __restrict__ rowp,
    const int* __restrict__ colp, const float* __restrict__ ea, const float* __restrict__ tdp,
    const u16* __restrict__ B1s, const float* __restrict__ W1tail, const float* __restrict__ b1,
    const u16* __restrict__ B2s, const float* __restrict__ b2v,
    const float* __restrict__ W3, const float* __restrict__ b3, float* __restrict__ out){
    __shared__ __align__(16) u16 ldsX[8192];    // 16 KB: one-k32 B fragment chunk (16 ntiles GEMM1 / 8 ntiles GEMM2)
    __shared__ __align__(16) u16 ldsZ[32768];   // 64 KB: z1, 8 groups x 16 rows x 256 cols, xor-swizzled
    int t = threadIdx.x, wave = t >> 6, lane = t & 63;
    int m0 = blockIdx.x * 128;
    int ml = lane & 15, g = lane >> 4;
    int mgrp  = wave >> 1;      // 0..3: edge group of 32
    int nhalf = wave & 1;       // 0..1: N half
    int e0 = m0 + mgrp * 32 + ml;      if (e0 > NE - 1) e0 = NE - 1;
    int e1 = m0 + mgrp * 32 + 16 + ml; if (e1 > NE - 1) e1 = NE - 1;
    const u16* pr0 = h3b + rowp[e0] * 256;
    const u16* pc0 = h3b + colp[e0] * 256;
    const u16* pr1 = h3b + rowp[e1] * 256;
    const u16* pc1 = h3b + colp[e1] * 256;
    float td = tdp[0];

    // staging geometry: 512 threads -> 2 uint4 slots (GEMM1: 16 KB/chunk), 1 slot (GEMM2: 8 KB/chunk)
    int n0  = t >> 6;             // local ntile 0..7
    int o0  = (t & 63) * 8;
    int lw0 = n0 * 512 + o0;      // lds write offset, slot 0 (u16 units); slot1 = lw0 + 4096

    f32x4 acc[2][8] = {};
    {
        const u16* b0p = B1s + (n0 * 16) * 512 + o0;       // ntile n0
        uint4 p0 = *(const uint4*)(b0p);
        uint4 p1 = *(const uint4*)(b0p + 65536);           // ntile n0+8
        uint4 a0 = *(const uint4*)(pr0 + g * 8);
        uint4 a1 = *(const uint4*)(pr1 + g * 8);
        for (int kc = 0; kc < 16; kc++){
            __syncthreads();
            *(uint4*)(&ldsX[lw0]) = p0;
            *(uint4*)(&ldsX[lw0 + 4096]) = p1;
            if (kc < 15){
                p0 = *(const uint4*)(b0p + (kc + 1) * 512);
                p1 = *(const uint4*)(b0p + (kc + 1) * 512 + 65536);
            }
            __syncthreads();
            uint4 a0n = a0, a1n = a1;
            if (kc < 15){
                int kn = kc + 1;
                const u16* sA0 = ((kn < 8) ? pr0 : pc0) + (kn & 7) * 32 + g * 8;
                const u16* sA1 = ((kn < 8) ? pr1 : pc1) + (kn & 7) * 32 + g * 8;
                a0n = *(const uint4*)sA0;
                a1n = *(const uint4*)sA1;
            }
            bf16x8 af0 = __builtin_bit_cast(bf16x8, a0);
            bf16x8 af1 = __builtin_bit_cast(bf16x8, a1);
            #pragma unroll
            for (int nt = 0; nt < 8; nt++){
                bf16x8 bfr = __builtin_bit_cast(bf16x8, *(const uint4*)(&ldsX[((nhalf * 8 + nt) * 64 + lane) * 8]));
                acc[0][nt] = __builtin_amdgcn_mfma_f32_16x16x32_bf16(af0, bfr, acc[0][nt], 0, 0, 0);
                acc[1][nt] = __builtin_amdgcn_mfma_f32_16x16x32_bf16(af1, bfr, acc[1][nt], 0, 0, 0);
            }
            a0 = a0n; a1 = a1n;
        }
    }
    float eav[2][4];
    #pragma unroll
    for (int grp = 0; grp < 2; grp++){
        #pragma unroll
        for (int r = 0; r < 4; r++){
            int e = m0 + mgrp * 32 + grp * 16 + g * 4 + r; if (e > NE - 1) e = NE - 1;
            eav[grp][r] = ea[e];
        }
    }
    #pragma unroll
    for (int nt = 0; nt < 8; nt++){
        int n = (nhalf * 8 + nt) * 16 + ml;
        float add0 = b1[n] + td * W1tail[256 + n];
        float w512 = W1tail[n];
        #pragma unroll
        for (int grp = 0; grp < 2; grp++){
            int zb = (mgrp * 2 + grp) * 4096;
            #pragma unroll
            for (int r = 0; r < 4; r++){
                int row = g * 4 + r;
                float v = acc[grp][nt][r] + add0 + eav[grp][r] * w512;
                v = v > 0.f ? v : 0.f;
                int idx = zb + row * 256 + ((((n >> 3) ^ (row & 7)) << 3) | (n & 7));
                ldsZ[idx] = f2b(v);
            }
        }
    }
    f32x4 acc2[2][4] = {};
    {
        const u16* b2p = B2s + (n0 * 8) * 512 + o0;
        uint4 q0 = *(const uint4*)(b2p);
        for (int kc = 0; kc < 8; kc++){
            __syncthreads();            // kc=0: also fences ldsZ writes from all waves
            *(uint4*)(&ldsX[lw0]) = q0;
            if (kc < 7) q0 = *(const uint4*)(b2p + (kc + 1) * 512);
            __syncthreads();
            int kb = kc * 4 + g;
            bf16x8 af0 = __builtin_bit_cast(bf16x8, *(const uint4*)(&ldsZ[(mgrp * 2 + 0) * 4096 + ml * 256 + ((kb ^ (ml & 7)) << 3)]));
            bf16x8 af1 = __builtin_bit_cast(bf16x8, *(const uint4*)(&ldsZ[(mgrp * 2 + 1) * 4096 + ml * 256 + ((kb ^ (ml & 7)) << 3)]));
            #pragma unroll
            for (int nt = 0; nt < 4; nt++){
                bf16x8 bfr = __builtin_bit_cast(bf16x8, *(const uint4*)(&ldsX[((nhalf * 4 + nt) * 64 + lane) * 8]));
                acc2[0][nt] = __builtin_amdgcn_mfma_f32_16x16x32_bf16(af0, bfr, acc2[0][nt], 0, 0, 0);
                acc2[1][nt] = __builtin_amdgcn_mfma_f32_16x16x32_bf16(af1, bfr, acc2[1][nt], 0, 0, 0);
            }
        }
    }
    __syncthreads();                    // all ldsX reads done; reuse as fp32 partial buffer
    float* ldsP = (float*)ldsX;
    #pragma unroll
    for (int grp = 0; grp < 2; grp++){
        float s0 = 0.f, s1 = 0.f, s2 = 0.f, s3 = 0.f;
        #pragma unroll
        for (int nt = 0; nt < 4; nt++){
            int n = (nhalf * 4 + nt) * 16 + ml;
            float bn = b2v[n];
            float w3 = W3[n];
            float z;
            z = acc2[grp][nt][0] + bn; s0 += (z > 0.f ? z : 0.f) * w3;
            z = acc2[grp][nt][1] + bn; s1 += (z > 0.f ? z : 0.f) * w3;
            z = acc2[grp][nt][2] + bn; s2 += (z > 0.f ? z : 0.f) * w3;
            z = acc2[grp][nt][3] + bn; s3 += (z > 0.f ? z : 0.f) * w3;
        }
        #pragma unroll
        for (int d = 1; d < 16; d <<= 1){
            s0 += __shfl_xor(s0, d); s1 += __shfl_xor(s1, d);
            s2 += __shfl_xor(s2, d); s3 += __shfl_xor(s3, d);
        }
        if (ml == 0){
            int base = nhalf * 128 + mgrp * 32 + grp * 16 + g * 4;
            ldsP[base + 0] = s0;
            ldsP[base + 1] = s1;
            ldsP[base + 2] = s2;
            ldsP[base + 3] = s3;
        }
    }
    __syncthreads();
    if (t < 128){
        int e = m0 + t;
        if (e < NE) out[e] = ldsP[t] + ldsP[128 + t] + b3[0];
    }
}

__global__ void k_fillcode_f32(float* __restrict__ out, float c){
    int i = blockIdx.x * 256 + threadIdx.x;
    if (i < NE) out[i] = c;
}

extern "C" void kernel_launch(void* const* d_in, const int* in_sizes, int n_in,
                              void* d_out, int out_size, void* d_ws, size_t ws_size,
                              hipStream_t stream){
    float* out = (float*)d_out;

    static const int exp_sizes[19] = {60000,600000,300000,1,768,256,768,65536,256,65536,
                                      65536,256,65536,131584,256,32768,128,128,1};
    int bad = -1;
    if (n_in != 19) bad = 19;
    else for (int k = 0; k < 19; k++) if (in_sizes[k] != exp_sizes[k]){ bad = k; break; }
    if (bad >= 0){
        k_fillcode_f32<<<(NE + 255) / 256, 256, 0, stream>>>(out, 1000.f + 50.f * bad);
        return;
    }

    char* ws = (char*)d_ws;
    size_t off = 0;
    auto alloc = [&](size_t bytes) -> void* {
        void* p = ws + off;
        off += (bytes + 255) & ~(size_t)255;
        return p;
    };
    int*   deg   = (int*)alloc(NN * 4);
    int*   cur   = (int*)alloc(NN * 4);
    int*   offs  = (int*)alloc((NN + 1) * 4);
    float* invd  = (float*)alloc(NN * 4);
    int*   srcs  = (int*)alloc(NE * 4);
    u16*   h1b   = (u16*)alloc((size_t)NN * 256 * 2);
    u16*   h2b   = (u16*)alloc((size_t)NN * 256 * 2);
    u16*   h3b   = (u16*)alloc((size_t)NN * 256 * 2);
    u16*   aggb  = (u16*)alloc((size_t)NN * 256 * 2);
    u16*   WLs2  = (u16*)alloc(512 * 256 * 2);
    u16*   WLs3  = (u16*)alloc(512 * 256 * 2);
    u16*   B1s   = (u16*)alloc(512 * 256 * 2);
    u16*   B2s   = (u16*)alloc(256 * 128 * 2);
    if (off > ws_size){
        k_fillcode_f32<<<(NE + 255) / 256, 256, 0, stream>>>(out, 9000.f);
        return;
    }

    const float* x   = (const float*)d_in[0];
    const int*   ei  = (const int*)d_in[1];     // (2,E) int32: [row..., col...]
    const float* ea  = (const float*)d_in[2];
    const float* td  = (const float*)d_in[3];
    const float* Wl1 = (const float*)d_in[4];
    const float* bl1 = (const float*)d_in[5];
    const float* Wr1 = (const float*)d_in[6];
    const float* Wl2 = (const float*)d_in[7];
    const float* bl2 = (const float*)d_in[8];
    const float* Wr2 = (const float*)d_in[9];
    const float* Wl3 = (const float*)d_in[10];
    const float* bl3 = (const float*)d_in[11];
    const float* Wr3 = (const float*)d_in[12];
    const float* W1  = (const float*)d_in[13];
    const float* b1  = (const float*)d_in[14];
    const float* W2  = (const float*)d_in[15];
    const float* b2  = (const float*)d_in[16];
    const float* W3  = (const float*)d_in[17];
    const float* b3  = (const float*)d_in[18];

    hipMemsetAsync(deg, 0, (size_t)((char*)cur - (char*)deg) + NN * 4, stream);

    const int* rowv = ei;          // sources
    const int* colv = ei + NE;     // targets

    k_count<<<(NE + 255) / 256, 256, 0, stream>>>(colv, deg);
    k_scan <<<1, 1024, 0, stream>>>(deg, offs, invd);
    k_fill <<<(NE + 255) / 256, 256, 0, stream>>>(rowv, colv, offs, cur, srcs);

    // weight fragment prep
    k_swz_pair_f32<<<512, 256, 0, stream>>>(Wl2, Wr2, WLs2, 256, 256, 16);
    k_swz_pair_f32<<<512, 256, 0, stream>>>(Wl3, Wr3, WLs3, 256, 256, 16);
    k_swz_f32<<<512, 256, 0, stream>>>(W1, B1s, 256, 16);
    k_swz_f32<<<128, 256, 0, stream>>>(W2, B2s, 128, 8);

    // SAGE layer 1 (fp32 math, bf16 out)
    k_layer1<<<NN / 4, 256, 0, stream>>>(x, offs, srcs, invd, Wl1, bl1, Wr1, h1b);

    dim3 ggrid((NN + 63) / 64, 2);

    // SAGE layers 2,3: separate aggr (high TLP) + N-split staged GEMM
    k_aggr<<<NN / 4, 256, 0, stream>>>(h1b, offs, srcs, invd, aggb);
    k_gemm_node<<<ggrid, 256, 0, stream>>>(aggb, h1b, WLs2, bl2, h2b);

    k_aggr<<<NN / 4, 256, 0, stream>>>(h2b, offs, srcs, invd, aggb);
    k_gemm_node<<<ggrid, 256, 0, stream>>>(aggb, h2b, WLs3, bl3, h3b);

    // fused edge MLP, bf16 MFMA: 512 threads, M=32/wave, N-split wave pairs
    k_mlp_bf16<<<(NE + 127) / 128, 512, 0, stream>>>(h3b, rowv, colv, ea, td,
                                                     B1s, W1 + 512 * 256, b1, B2s, b2, W3, b3, out);
}

// Round 4
// 420.751 us; speedup vs baseline: 1.0438x; 1.0438x over previous
//
#include <hip/hip_runtime.h>

#define NN 20000
#define NE 300000

typedef unsigned short u16;
typedef unsigned int   u32;

typedef __bf16 bf16x8 __attribute__((ext_vector_type(8)));
typedef float  f32x4  __attribute__((ext_vector_type(4)));

__device__ __forceinline__ float b2f(u16 u){ u32 x = ((u32)u) << 16; return __builtin_bit_cast(float, x); }
__device__ __forceinline__ u16 f2b(float f){
    u32 x = __builtin_bit_cast(u32, f);
    u32 r = x + 0x7fffu + ((x >> 16) & 1u);
    return (u16)(r >> 16);
}

// async global->LDS, 16B per lane; LDS dest must be wave-uniform base (HW adds lane*16)
__device__ __forceinline__ void glds16(const u16* g, u16* l){
    __builtin_amdgcn_global_load_lds((const __attribute__((address_space(1))) unsigned int*)g,
                                     (__attribute__((address_space(3))) unsigned int*)l, 16, 0, 0);
}

// ---------------- CSR build: bucket edges by col (target), store row (source) ----------------
__global__ void k_count(const int* __restrict__ key, int* __restrict__ deg){
    int e = blockIdx.x * 256 + threadIdx.x;
    if (e < NE){
        int c = key[e];
        if (c >= 0 && c < NN) atomicAdd(&deg[c], 1);
    }
}

__global__ void k_scan(const int* __restrict__ deg, int* __restrict__ offs, float* __restrict__ invd){
    __shared__ int part[1024];
    int t = threadIdx.x;
    int base = t * 20;
    int s = 0;
    for (int i = 0; i < 20; i++){ int idx = base + i; if (idx < NN) s += deg[idx]; }
    part[t] = s; __syncthreads();
    for (int d = 1; d < 1024; d <<= 1){
        int v = (t >= d) ? part[t - d] : 0;
        __syncthreads();
        part[t] += v;
        __syncthreads();
    }
    int run = part[t] - s;
    for (int i = 0; i < 20; i++){
        int idx = base + i;
        if (idx < NN){
            offs[idx] = run;
            int d0 = deg[idx];
            run += d0;
            invd[idx] = 1.0f / (float)(d0 > 0 ? d0 : 1);
        }
    }
    if (t == 1023) offs[NN] = part[1023];
}

__global__ void k_fill(const int* __restrict__ val, const int* __restrict__ key,
                       const int* __restrict__ offs, int* __restrict__ cur, int* __restrict__ srcs){
    int e = blockIdx.x * 256 + threadIdx.x;
    if (e < NE){
        int c = key[e];
        if (c >= 0 && c < NN){
            int slot = offs[c] + atomicAdd(&cur[c], 1);
            int r = val[e];
            srcs[slot] = (r >= 0 && r < NN) ? r : 0;
        }
    }
}

// ---------------- weight swizzle fp32 -> bf16 MFMA B-fragments ----------------
__global__ void k_swz_f32(const float* __restrict__ W, u16* __restrict__ dst, int N, int KT){
    int t = blockIdx.x * 256 + threadIdx.x;
    int j = t & 7, lane = (t >> 3) & 63, tile = t >> 9;
    int ktile = tile % KT, ntile = tile / KT;
    int k = ktile * 32 + ((lane >> 4) << 3) + j;
    int n = ntile * 16 + (lane & 15);
    dst[t] = f2b(W[k * N + n]);
}

__global__ void k_swz_pair_f32(const float* __restrict__ A, const float* __restrict__ B, u16* __restrict__ dst,
                               int halfK, int N, int KT){
    int t = blockIdx.x * 256 + threadIdx.x;
    int j = t & 7, lane = (t >> 3) & 63, tile = t >> 9;
    int ktile = tile % KT, ntile = tile / KT;
    int k = ktile * 32 + ((lane >> 4) << 3) + j;
    int n = ntile * 16 + (lane & 15);
    dst[t] = f2b((k < halfK) ? A[k * N + n] : B[(k - halfK) * N + n]);
}

// ---------------- SAGE layer 1 (din=3): fp32 math, bf16 output ----------------
__global__ void k_layer1(const float* __restrict__ x, const int* __restrict__ offs, const int* __restrict__ srcs,
                         const float* __restrict__ invd, const float* __restrict__ Wl, const float* __restrict__ bl,
                         const float* __restrict__ Wr, u16* __restrict__ h1){
    int node = blockIdx.x * 4 + (threadIdx.x >> 6);
    int lane = threadIdx.x & 63;
    int st = offs[node], en = offs[node + 1];
    float s0 = 0.f, s1 = 0.f, s2 = 0.f;
    for (int j = st + lane; j < en; j += 64){
        int s = srcs[j];
        s0 += x[s * 3 + 0]; s1 += x[s * 3 + 1]; s2 += x[s * 3 + 2];
    }
    #pragma unroll
    for (int d = 1; d < 64; d <<= 1){
        s0 += __shfl_xor(s0, d); s1 += __shfl_xor(s1, d); s2 += __shfl_xor(s2, d);
    }
    float inv = invd[node];
    float a0 = s0 * inv, a1 = s1 * inv, a2 = s2 * inv;
    float xi0 = x[node * 3 + 0], xi1 = x[node * 3 + 1], xi2 = x[node * 3 + 2];
    int f0 = lane * 4;
    ushort4 stv;
    u16* sp = (u16*)&stv;
    #pragma unroll
    for (int r = 0; r < 4; r++){
        int n = f0 + r;
        float o = a0 * Wl[n] + a1 * Wl[256 + n] + a2 * Wl[512 + n]
                + xi0 * Wr[n] + xi1 * Wr[256 + n] + xi2 * Wr[512 + n] + bl[n];
        sp[r] = f2b(o > 0.f ? o : 0.f);
    }
    *(ushort4*)(h1 + node * 256 + f0) = stv;
}

// ---------------- mean aggregation over CSR: 16B/lane, 2 rows in flight per wave ----------------
__global__ void k_aggr(const u16* __restrict__ hin, const int* __restrict__ offs, const int* __restrict__ srcs,
                       const float* __restrict__ invd, u16* __restrict__ aggr){
    int node = blockIdx.x * 4 + (threadIdx.x >> 6);
    int lane = threadIdx.x & 63;
    int st = offs[node], en = offs[node + 1];
    int half = lane >> 5;
    int c0 = (lane & 31) * 8;
    float a0=0.f,a1=0.f,a2=0.f,a3=0.f,a4=0.f,a5=0.f,a6=0.f,a7=0.f;
    for (int j = st + half; j < en; j += 2){
        int s = srcs[j];
        uint4 v = *(const uint4*)(hin + s * 256 + c0);
        a0 += b2f((u16)v.x); a1 += b2f((u16)(v.x >> 16));
        a2 += b2f((u16)v.y); a3 += b2f((u16)(v.y >> 16));
        a4 += b2f((u16)v.z); a5 += b2f((u16)(v.z >> 16));
        a6 += b2f((u16)v.w); a7 += b2f((u16)(v.w >> 16));
    }
    a0 += __shfl_xor(a0, 32); a1 += __shfl_xor(a1, 32);
    a2 += __shfl_xor(a2, 32); a3 += __shfl_xor(a3, 32);
    a4 += __shfl_xor(a4, 32); a5 += __shfl_xor(a5, 32);
    a6 += __shfl_xor(a6, 32); a7 += __shfl_xor(a7, 32);
    if (half == 0){
        float inv = invd[node];
        uint4 o;
        o.x = (u32)f2b(a0 * inv) | ((u32)f2b(a1 * inv) << 16);
        o.y = (u32)f2b(a2 * inv) | ((u32)f2b(a3 * inv) << 16);
        o.z = (u32)f2b(a4 * inv) | ((u32)f2b(a5 * inv) << 16);
        o.w = (u32)f2b(a6 * inv) | ((u32)f2b(a7 * inv) << 16);
        *(uint4*)(aggr + node * 256 + c0) = o;
    }
}

// ---------------- node dense layer: relu([aggr|hin] @ Bs + bias), MFMA, N-split grid ----------------
// grid (313, 2): block computes 64 rows x 128 cols. (round-0 proven version; not the bottleneck)
__global__ __launch_bounds__(256) void k_gemm_node(const u16* __restrict__ aggr, const u16* __restrict__ hin,
    const u16* __restrict__ Bs, const float* __restrict__ bias, u16* __restrict__ out){
    __shared__ __align__(16) u16 ldsB[4096];   // 8 KB: one k32-chunk, 8 local ntiles
    int t = threadIdx.x, wave = t >> 6, lane = t & 63;
    int m0 = blockIdx.x * 64 + wave * 16;
    int nb = blockIdx.y * 8;                   // global ntile base (8 ntiles = 128 cols)
    int ml = lane & 15, g = lane >> 4;
    int arow = m0 + ml; if (arow > NN - 1) arow = NN - 1;
    const u16* pa = aggr + arow * 256;
    const u16* ph = hin  + arow * 256;

    int flat0 = t * 8, flat1 = (256 + t) * 8;
    int s0i = flat0 >> 9, o0 = flat0 & 511;    // local ntile 0..3
    int s1i = flat1 >> 9, o1 = flat1 & 511;    // local ntile 4..7
    uint4 p0 = *(const uint4*)(Bs + ((nb + s0i) * 16 + 0) * 512 + o0);
    uint4 p1 = *(const uint4*)(Bs + ((nb + s1i) * 16 + 0) * 512 + o1);

    f32x4 acc[8] = {};
    for (int k32 = 0; k32 < 16; k32++){
        __syncthreads();
        *(uint4*)(&ldsB[s0i * 512 + o0]) = p0;
        *(uint4*)(&ldsB[s1i * 512 + o1]) = p1;
        if (k32 < 15){
            p0 = *(const uint4*)(Bs + ((nb + s0i) * 16 + k32 + 1) * 512 + o0);
            p1 = *(const uint4*)(Bs + ((nb + s1i) * 16 + k32 + 1) * 512 + o1);
        }
        __syncthreads();
        const u16* asrc = (k32 < 8) ? (pa + k32 * 32) : (ph + (k32 - 8) * 32);
        bf16x8 af = __builtin_bit_cast(bf16x8, *(const uint4*)(asrc + g * 8));
        #pragma unroll
        for (int nt = 0; nt < 8; nt++){
            bf16x8 bfr = __builtin_bit_cast(bf16x8, *(const uint4*)(&ldsB[(nt * 64 + lane) * 8]));
            acc[nt] = __builtin_amdgcn_mfma_f32_16x16x32_bf16(af, bfr, acc[nt], 0, 0, 0);
        }
    }
    #pragma unroll
    for (int nt = 0; nt < 8; nt++){
        int n = (nb + nt) * 16 + ml;
        float bn = bias[n];
        #pragma unroll
        for (int r = 0; r < 4; r++){
            int rowg = m0 + g * 4 + r;
            if (rowg < NN){
                float v = acc[nt][r] + bn;
                out[rowg * 256 + n] = f2b(v > 0.f ? v : 0.f);
            }
        }
    }
}

// ---------------- bf16-MFMA edge MLP: 512 threads, 128 edges/block ----------------
// Wave = (mgrp 0..3, nhalf 0..1): M=32 edges/wave, N split across wave pairs.
// B staged via global_load_lds (no staging regs, no ds_writes); A single-buffer prefetch.
// acc[2][8]=64 AGPR + ~50 VGPR fits the 128-reg budget of __launch_bounds__(512,4).
__global__ __launch_bounds__(512, 4) void k_mlp_bf16(const u16* __restrict__ h3b, const int* __restrict__ rowp,
    const int* __restrict__ colp, const float* __restrict__ ea, const float* __restrict__ tdp,
    const u16* __restrict__ B1s, const float* __restrict__ W1tail, const float* __restrict__ b1,
    const u16* __restrict__ B2s, const float* __restrict__ b2v,
    const float* __restrict__ W3, const float* __restrict__ b3, float* __restrict__ out){
    __shared__ __align__(16) u16 ldsX[8192];    // 16 KB: one-k32 B fragment chunk
    __shared__ __align__(16) u16 ldsZ[32768];   // 64 KB: z1, 8 groups x 16 rows x 256 cols, xor-swizzled
    int t = threadIdx.x, wave = t >> 6, lane = t & 63;
    int m0 = blockIdx.x * 128;
    int ml = lane & 15, g = lane >> 4;
    int mgrp  = wave >> 1;      // 0..3: edge group of 32
    int nhalf = wave & 1;       // 0..1: N half
    int e0 = m0 + mgrp * 32 + ml;      if (e0 > NE - 1) e0 = NE - 1;
    int e1 = m0 + mgrp * 32 + 16 + ml; if (e1 > NE - 1) e1 = NE - 1;
    const u16* pr0 = h3b + rowp[e0] * 256;
    const u16* pc0 = h3b + colp[e0] * 256;
    const u16* pr1 = h3b + rowp[e1] * 256;
    const u16* pc1 = h3b + colp[e1] * 256;
    float td = tdp[0];

    // glds staging: GEMM1 chunk = 16 fragments x 1 KB; wave w DMAs fragments {2w, 2w+1}.
    // LDS layout matches B1s fragment order exactly: frag f at byte f*1024, lane*16 within.
    int fr0 = wave * 2, fr1 = wave * 2 + 1;
    const u16* g1a = B1s + (fr0 * 16) * 512 + lane * 8;   // + kc*512 per chunk
    const u16* g1b = B1s + (fr1 * 16) * 512 + lane * 8;
    u16* lx0 = &ldsX[fr0 * 512];                          // wave-uniform dests
    u16* lx1 = &ldsX[fr1 * 512];

    glds16(g1a, lx0);                                     // prologue: chunk 0
    glds16(g1b, lx1);

    uint4 a0 = *(const uint4*)(pr0 + g * 8);
    uint4 a1 = *(const uint4*)(pr1 + g * 8);

    f32x4 acc[2][8] = {};
    for (int kc = 0; kc < 16; kc++){
        __syncthreads();                    // vmcnt(0) drain -> chunk kc + A(kc) ready; prev reads done
        bf16x8 af0 = __builtin_bit_cast(bf16x8, a0);
        bf16x8 af1 = __builtin_bit_cast(bf16x8, a1);
        #pragma unroll
        for (int nt = 0; nt < 8; nt++){
            bf16x8 bfr = __builtin_bit_cast(bf16x8, *(const uint4*)(&ldsX[((nhalf * 8 + nt) * 64 + lane) * 8]));
            acc[0][nt] = __builtin_amdgcn_mfma_f32_16x16x32_bf16(af0, bfr, acc[0][nt], 0, 0, 0);
            acc[1][nt] = __builtin_amdgcn_mfma_f32_16x16x32_bf16(af1, bfr, acc[1][nt], 0, 0, 0);
        }
        if (kc < 15){                       // A prefetch into same regs (live ranges disjoint)
            int kn = kc + 1;
            const u16* sA0 = ((kn < 8) ? pr0 : pc0) + (kn & 7) * 32 + g * 8;
            const u16* sA1 = ((kn < 8) ? pr1 : pc1) + (kn & 7) * 32 + g * 8;
            a0 = *(const uint4*)sA0;
            a1 = *(const uint4*)sA1;
        }
        __syncthreads();                    // all waves done reading chunk kc
        if (kc < 15){
            glds16(g1a + (kc + 1) * 512, lx0);
            glds16(g1b + (kc + 1) * 512, lx1);
        }
    }

    // GEMM2 staging prologue: chunk 0 of B2s (8 fragments; wave w DMAs fragment w).
    // Safe: last GEMM1 bottom barrier passed -> all ldsX reads complete.
    const u16* g2 = B2s + (wave * 8) * 512 + lane * 8;
    u16* lx2 = &ldsX[wave * 512];
    glds16(g2, lx2);

    // z1 epilogue (overlaps the glds latency)
    float eav[2][4];
    #pragma unroll
    for (int grp = 0; grp < 2; grp++){
        #pragma unroll
        for (int r = 0; r < 4; r++){
            int e = m0 + mgrp * 32 + grp * 16 + g * 4 + r; if (e > NE - 1) e = NE - 1;
            eav[grp][r] = ea[e];
        }
    }
    #pragma unroll
    for (int nt = 0; nt < 8; nt++){
        int n = (nhalf * 8 + nt) * 16 + ml;
        float add0 = b1[n] + td * W1tail[256 + n];
        float w512 = W1tail[n];
        #pragma unroll
        for (int grp = 0; grp < 2; grp++){
            int zb = (mgrp * 2 + grp) * 4096;
            #pragma unroll
            for (int r = 0; r < 4; r++){
                int row = g * 4 + r;
                float v = acc[grp][nt][r] + add0 + eav[grp][r] * w512;
                v = v > 0.f ? v : 0.f;
                int idx = zb + row * 256 + ((((n >> 3) ^ (row & 7)) << 3) | (n & 7));
                ldsZ[idx] = f2b(v);
            }
        }
    }

    f32x4 acc2[2][4] = {};
    for (int kc = 0; kc < 8; kc++){
        __syncthreads();                    // B2 chunk kc landed; ldsZ writes visible (kc=0)
        int kb = kc * 4 + g;
        bf16x8 af0 = __builtin_bit_cast(bf16x8, *(const uint4*)(&ldsZ[(mgrp * 2 + 0) * 4096 + ml * 256 + ((kb ^ (ml & 7)) << 3)]));
        bf16x8 af1 = __builtin_bit_cast(bf16x8, *(const uint4*)(&ldsZ[(mgrp * 2 + 1) * 4096 + ml * 256 + ((kb ^ (ml & 7)) << 3)]));
        #pragma unroll
        for (int nt = 0; nt < 4; nt++){
            bf16x8 bfr = __builtin_bit_cast(bf16x8, *(const uint4*)(&ldsX[((nhalf * 4 + nt) * 64 + lane) * 8]));
            acc2[0][nt] = __builtin_amdgcn_mfma_f32_16x16x32_bf16(af0, bfr, acc2[0][nt], 0, 0, 0);
            acc2[1][nt] = __builtin_amdgcn_mfma_f32_16x16x32_bf16(af1, bfr, acc2[1][nt], 0, 0, 0);
        }
        __syncthreads();                    // all waves done reading chunk kc
        if (kc < 7) glds16(g2 + (kc + 1) * 512, lx2);
    }

    // ldsX reuse as fp32 partial buffer (all ldsX reads done; barrier passed)
    float* ldsP = (float*)ldsX;
    #pragma unroll
    for (int grp = 0; grp < 2; grp++){
        float s0 = 0.f, s1 = 0.f, s2 = 0.f, s3 = 0.f;
        #pragma unroll
        for (int nt = 0; nt < 4; nt++){
            int n = (nhalf * 4 + nt) * 16 + ml;
            float bn = b2v[n];
            float w3 = W3[n];
            float z;
            z = acc2[grp][nt][0] + bn; s0 += (z > 0.f ? z : 0.f) * w3;
            z = acc2[grp][nt][1] + bn; s1 += (z > 0.f ? z : 0.f) * w3;
            z = acc2[grp][nt][2] + bn; s2 += (z > 0.f ? z : 0.f) * w3;
            z = acc2[grp][nt][3] + bn; s3 += (z > 0.f ? z : 0.f) * w3;
        }
        #pragma unroll
        for (int d = 1; d < 16; d <<= 1){
            s0 += __shfl_xor(s0, d); s1 += __shfl_xor(s1, d);
            s2 += __shfl_xor(s2, d); s3 += __shfl_xor(s3, d);
        }
        if (ml == 0){
            int base = nhalf * 128 + mgrp * 32 + grp * 16 + g * 4;
            ldsP[base + 0] = s0;
            ldsP[base + 1] = s1;
            ldsP[base + 2] = s2;
            ldsP[base + 3] = s3;
        }
    }
    __syncthreads();
    if (t < 128){
        int e = m0 + t;
        if (e < NE) out[e] = ldsP[t] + ldsP[128 + t] + b3[0];
    }
}

__global__ void k_fillcode_f32(float* __restrict__ out, float c){
    int i = blockIdx.x * 256 + threadIdx.x;
    if (i < NE) out[i] = c;
}

extern "C" void kernel_launch(void* const* d_in, const int* in_sizes, int n_in,
                              void* d_out, int out_size, void* d_ws, size_t ws_size,
                              hipStream_t stream){
    float* out = (float*)d_out;

    static const int exp_sizes[19] = {60000,600000,300000,1,768,256,768,65536,256,65536,
                                      65536,256,65536,131584,256,32768,128,128,1};
    int bad = -1;
    if (n_in != 19) bad = 19;
    else for (int k = 0; k < 19; k++) if (in_sizes[k] != exp_sizes[k]){ bad = k; break; }
    if (bad >= 0){
        k_fillcode_f32<<<(NE + 255) / 256, 256, 0, stream>>>(out, 1000.f + 50.f * bad);
        return;
    }

    char* ws = (char*)d_ws;
    size_t off = 0;
    auto alloc = [&](size_t bytes) -> void* {
        void* p = ws + off;
        off += (bytes + 255) & ~(size_t)255;
        return p;
    };
    int*   deg   = (int*)alloc(NN * 4);
    int*   cur   = (int*)alloc(NN * 4);
    int*   offs  = (int*)alloc((NN + 1) * 4);
    float* invd  = (float*)alloc(NN * 4);
    int*   srcs  = (int*)alloc(NE * 4);
    u16*   h1b   = (u16*)alloc((size_t)NN * 256 * 2);
    u16*   h2b   = (u16*)alloc((size_t)NN * 256 * 2);
    u16*   h3b   = (u16*)alloc((size_t)NN * 256 * 2);
    u16*   aggb  = (u16*)alloc((size_t)NN * 256 * 2);
    u16*   WLs2  = (u16*)alloc(512 * 256 * 2);
    u16*   WLs3  = (u16*)alloc(512 * 256 * 2);
    u16*   B1s   = (u16*)alloc(512 * 256 * 2);
    u16*   B2s   = (u16*)alloc(256 * 128 * 2);
    if (off > ws_size){
        k_fillcode_f32<<<(NE + 255) / 256, 256, 0, stream>>>(out, 9000.f);
        return;
    }

    const float* x   = (const float*)d_in[0];
    const int*   ei  = (const int*)d_in[1];     // (2,E) int32: [row..., col...]
    const float* ea  = (const float*)d_in[2];
    const float* td  = (const float*)d_in[3];
    const float* Wl1 = (const float*)d_in[4];
    const float* bl1 = (const float*)d_in[5];
    const float* Wr1 = (const float*)d_in[6];
    const float* Wl2 = (const float*)d_in[7];
    const float* bl2 = (const float*)d_in[8];
    const float* Wr2 = (const float*)d_in[9];
    const float* Wl3 = (const float*)d_in[10];
    const float* bl3 = (const float*)d_in[11];
    const float* Wr3 = (const float*)d_in[12];
    const float* W1  = (const float*)d_in[13];
    const float* b1  = (const float*)d_in[14];
    const float* W2  = (const float*)d_in[15];
    const float* b2  = (const float*)d_in[16];
    const float* W3  = (const float*)d_in[17];
    const float* b3  = (const float*)d_in[18];

    hipMemsetAsync(deg, 0, (size_t)((char*)cur - (char*)deg) + NN * 4, stream);

    const int* rowv = ei;          // sources
    const int* colv = ei + NE;     // targets

    k_count<<<(NE + 255) / 256, 256, 0, stream>>>(colv, deg);
    k_scan <<<1, 1024, 0, stream>>>(deg, offs, invd);
    k_fill <<<(NE + 255) / 256, 256, 0, stream>>>(rowv, colv, offs, cur, srcs);

    // weight fragment prep
    k_swz_pair_f32<<<512, 256, 0, stream>>>(Wl2, Wr2, WLs2, 256, 256, 16);
    k_swz_pair_f32<<<512, 256, 0, stream>>>(Wl3, Wr3, WLs3, 256, 256, 16);
    k_swz_f32<<<512, 256, 0, stream>>>(W1, B1s, 256, 16);
    k_swz_f32<<<128, 256, 0, stream>>>(W2, B2s, 128, 8);

    // SAGE layer 1 (fp32 math, bf16 out)
    k_layer1<<<NN / 4, 256, 0, stream>>>(x, offs, srcs, invd, Wl1, bl1, Wr1, h1b);

    dim3 ggrid((NN + 63) / 64, 2);

    // SAGE layers 2,3: separate aggr (high TLP) + N-split staged GEMM
    k_aggr<<<NN / 4, 256, 0, stream>>>(h1b, offs, srcs, invd, aggb);
    k_gemm_node<<<ggrid, 256, 0, stream>>>(aggb, h1b, WLs2, bl2, h2b);

    k_aggr<<<NN / 4, 256, 0, stream>>>(h2b, offs, srcs, invd, aggb);
    k_gemm_node<<<ggrid, 256, 0, stream>>>(aggb, h2b, WLs3, bl3, h3b);

    // fused edge MLP: glds-staged B, M=32/wave, N-split wave pairs
    k_mlp_bf16<<<(NE + 127) / 128, 512, 0, stream>>>(h3b, rowv, colv, ea, td,
                                                     B1s, W1 + 512 * 256, b1, B2s, b2, W3, b3, out);
}

// Round 5
// 402.625 us; speedup vs baseline: 1.0908x; 1.0450x over previous
//
#include <hip/hip_runtime.h>

#define NN 20000
#define NE 300000

typedef unsigned short u16;
typedef unsigned int   u32;

typedef __bf16 bf16x8 __attribute__((ext_vector_type(8)));
typedef float  f32x4  __attribute__((ext_vector_type(4)));

__device__ __forceinline__ float b2f(u16 u){ u32 x = ((u32)u) << 16; return __builtin_bit_cast(float, x); }
__device__ __forceinline__ u16 f2b(float f){
    u32 x = __builtin_bit_cast(u32, f);
    u32 r = x + 0x7fffu + ((x >> 16) & 1u);
    return (u16)(r >> 16);
}

// ---------------- CSR build: bucket edges by col (target), store row (source) ----------------
__global__ void k_count(const int* __restrict__ key, int* __restrict__ deg){
    int e = blockIdx.x * 256 + threadIdx.x;
    if (e < NE){
        int c = key[e];
        if (c >= 0 && c < NN) atomicAdd(&deg[c], 1);
    }
}

__global__ void k_scan(const int* __restrict__ deg, int* __restrict__ offs, float* __restrict__ invd){
    __shared__ int part[1024];
    int t = threadIdx.x;
    int base = t * 20;
    int s = 0;
    for (int i = 0; i < 20; i++){ int idx = base + i; if (idx < NN) s += deg[idx]; }
    part[t] = s; __syncthreads();
    for (int d = 1; d < 1024; d <<= 1){
        int v = (t >= d) ? part[t - d] : 0;
        __syncthreads();
        part[t] += v;
        __syncthreads();
    }
    int run = part[t] - s;
    for (int i = 0; i < 20; i++){
        int idx = base + i;
        if (idx < NN){
            offs[idx] = run;
            int d0 = deg[idx];
            run += d0;
            invd[idx] = 1.0f / (float)(d0 > 0 ? d0 : 1);
        }
    }
    if (t == 1023) offs[NN] = part[1023];
}

__global__ void k_fill(const int* __restrict__ val, const int* __restrict__ key,
                       const int* __restrict__ offs, int* __restrict__ cur, int* __restrict__ srcs){
    int e = blockIdx.x * 256 + threadIdx.x;
    if (e < NE){
        int c = key[e];
        if (c >= 0 && c < NN){
            int slot = offs[c] + atomicAdd(&cur[c], 1);
            int r = val[e];
            srcs[slot] = (r >= 0 && r < NN) ? r : 0;
        }
    }
}

// ---------------- weight swizzle fp32 -> bf16 MFMA B-fragments ----------------
__global__ void k_swz_f32(const float* __restrict__ W, u16* __restrict__ dst, int N, int KT){
    int t = blockIdx.x * 256 + threadIdx.x;
    int j = t & 7, lane = (t >> 3) & 63, tile = t >> 9;
    int ktile = tile % KT, ntile = tile / KT;
    int k = ktile * 32 + ((lane >> 4) << 3) + j;
    int n = ntile * 16 + (lane & 15);
    dst[t] = f2b(W[k * N + n]);
}

__global__ void k_swz_pair_f32(const float* __restrict__ A, const float* __restrict__ B, u16* __restrict__ dst,
                               int halfK, int N, int KT){
    int t = blockIdx.x * 256 + threadIdx.x;
    int j = t & 7, lane = (t >> 3) & 63, tile = t >> 9;
    int ktile = tile % KT, ntile = tile / KT;
    int k = ktile * 32 + ((lane >> 4) << 3) + j;
    int n = ntile * 16 + (lane & 15);
    dst[t] = f2b((k < halfK) ? A[k * N + n] : B[(k - halfK) * N + n]);
}

// cat-swizzle for node-level P GEMM: B_cat[k][n'] = n'<256 ? W1[k][n'] : W1[256+k][n'-256]
// fragment order: (ntile 0..31) major, (ktile 0..7) minor — matches k_gemm_p's indexing.
__global__ void k_swz_cat(const float* __restrict__ W1, u16* __restrict__ dst){
    int t = blockIdx.x * 256 + threadIdx.x;       // 512 blocks x 256 = 131072
    int j = t & 7, lane = (t >> 3) & 63, tile = t >> 9;
    int ktile = tile & 7, ntile = tile >> 3;
    int k = ktile * 32 + ((lane >> 4) << 3) + j;  // 0..255
    int n = ntile * 16 + (lane & 15);             // 0..511
    float v = (n < 256) ? W1[k * 256 + n] : W1[(256 + k) * 256 + (n - 256)];
    dst[t] = f2b(v);
}

// ---------------- SAGE layer 1 (din=3): fp32 math, bf16 output ----------------
__global__ void k_layer1(const float* __restrict__ x, const int* __restrict__ offs, const int* __restrict__ srcs,
                         const float* __restrict__ invd, const float* __restrict__ Wl, const float* __restrict__ bl,
                         const float* __restrict__ Wr, u16* __restrict__ h1){
    int node = blockIdx.x * 4 + (threadIdx.x >> 6);
    int lane = threadIdx.x & 63;
    int st = offs[node], en = offs[node + 1];
    float s0 = 0.f, s1 = 0.f, s2 = 0.f;
    for (int j = st + lane; j < en; j += 64){
        int s = srcs[j];
        s0 += x[s * 3 + 0]; s1 += x[s * 3 + 1]; s2 += x[s * 3 + 2];
    }
    #pragma unroll
    for (int d = 1; d < 64; d <<= 1){
        s0 += __shfl_xor(s0, d); s1 += __shfl_xor(s1, d); s2 += __shfl_xor(s2, d);
    }
    float inv = invd[node];
    float a0 = s0 * inv, a1 = s1 * inv, a2 = s2 * inv;
    float xi0 = x[node * 3 + 0], xi1 = x[node * 3 + 1], xi2 = x[node * 3 + 2];
    int f0 = lane * 4;
    ushort4 stv;
    u16* sp = (u16*)&stv;
    #pragma unroll
    for (int r = 0; r < 4; r++){
        int n = f0 + r;
        float o = a0 * Wl[n] + a1 * Wl[256 + n] + a2 * Wl[512 + n]
                + xi0 * Wr[n] + xi1 * Wr[256 + n] + xi2 * Wr[512 + n] + bl[n];
        sp[r] = f2b(o > 0.f ? o : 0.f);
    }
    *(ushort4*)(h1 + node * 256 + f0) = stv;
}

// ---------------- mean aggregation over CSR: 16B/lane, 2 rows in flight per wave ----------------
__global__ void k_aggr(const u16* __restrict__ hin, const int* __restrict__ offs, const int* __restrict__ srcs,
                       const float* __restrict__ invd, u16* __restrict__ aggr){
    int node = blockIdx.x * 4 + (threadIdx.x >> 6);
    int lane = threadIdx.x & 63;
    int st = offs[node], en = offs[node + 1];
    int half = lane >> 5;
    int c0 = (lane & 31) * 8;
    float a0=0.f,a1=0.f,a2=0.f,a3=0.f,a4=0.f,a5=0.f,a6=0.f,a7=0.f;
    for (int j = st + half; j < en; j += 2){
        int s = srcs[j];
        uint4 v = *(const uint4*)(hin + s * 256 + c0);
        a0 += b2f((u16)v.x); a1 += b2f((u16)(v.x >> 16));
        a2 += b2f((u16)v.y); a3 += b2f((u16)(v.y >> 16));
        a4 += b2f((u16)v.z); a5 += b2f((u16)(v.z >> 16));
        a6 += b2f((u16)v.w); a7 += b2f((u16)(v.w >> 16));
    }
    a0 += __shfl_xor(a0, 32); a1 += __shfl_xor(a1, 32);
    a2 += __shfl_xor(a2, 32); a3 += __shfl_xor(a3, 32);
    a4 += __shfl_xor(a4, 32); a5 += __shfl_xor(a5, 32);
    a6 += __shfl_xor(a6, 32); a7 += __shfl_xor(a7, 32);
    if (half == 0){
        float inv = invd[node];
        uint4 o;
        o.x = (u32)f2b(a0 * inv) | ((u32)f2b(a1 * inv) << 16);
        o.y = (u32)f2b(a2 * inv) | ((u32)f2b(a3 * inv) << 16);
        o.z = (u32)f2b(a4 * inv) | ((u32)f2b(a5 * inv) << 16);
        o.w = (u32)f2b(a6 * inv) | ((u32)f2b(a7 * inv) << 16);
        *(uint4*)(aggr + node * 256 + c0) = o;
    }
}

// ---------------- node dense layer: relu([aggr|hin] @ Bs + bias), MFMA, N-split grid ----------------
// grid (313, 2): block computes 64 rows x 128 cols. (round-0 proven version)
__global__ __launch_bounds__(256) void k_gemm_node(const u16* __restrict__ aggr, const u16* __restrict__ hin,
    const u16* __restrict__ Bs, const float* __restrict__ bias, u16* __restrict__ out){
    __shared__ __align__(16) u16 ldsB[4096];   // 8 KB: one k32-chunk, 8 local ntiles
    int t = threadIdx.x, wave = t >> 6, lane = t & 63;
    int m0 = blockIdx.x * 64 + wave * 16;
    int nb = blockIdx.y * 8;                   // global ntile base (8 ntiles = 128 cols)
    int ml = lane & 15, g = lane >> 4;
    int arow = m0 + ml; if (arow > NN - 1) arow = NN - 1;
    const u16* pa = aggr + arow * 256;
    const u16* ph = hin  + arow * 256;

    int flat0 = t * 8, flat1 = (256 + t) * 8;
    int s0i = flat0 >> 9, o0 = flat0 & 511;    // local ntile 0..3
    int s1i = flat1 >> 9, o1 = flat1 & 511;    // local ntile 4..7
    uint4 p0 = *(const uint4*)(Bs + ((nb + s0i) * 16 + 0) * 512 + o0);
    uint4 p1 = *(const uint4*)(Bs + ((nb + s1i) * 16 + 0) * 512 + o1);

    f32x4 acc[8] = {};
    for (int k32 = 0; k32 < 16; k32++){
        __syncthreads();
        *(uint4*)(&ldsB[s0i * 512 + o0]) = p0;
        *(uint4*)(&ldsB[s1i * 512 + o1]) = p1;
        if (k32 < 15){
            p0 = *(const uint4*)(Bs + ((nb + s0i) * 16 + k32 + 1) * 512 + o0);
            p1 = *(const uint4*)(Bs + ((nb + s1i) * 16 + k32 + 1) * 512 + o1);
        }
        __syncthreads();
        const u16* asrc = (k32 < 8) ? (pa + k32 * 32) : (ph + (k32 - 8) * 32);
        bf16x8 af = __builtin_bit_cast(bf16x8, *(const uint4*)(asrc + g * 8));
        #pragma unroll
        for (int nt = 0; nt < 8; nt++){
            bf16x8 bfr = __builtin_bit_cast(bf16x8, *(const uint4*)(&ldsB[(nt * 64 + lane) * 8]));
            acc[nt] = __builtin_amdgcn_mfma_f32_16x16x32_bf16(af, bfr, acc[nt], 0, 0, 0);
        }
    }
    #pragma unroll
    for (int nt = 0; nt < 8; nt++){
        int n = (nb + nt) * 16 + ml;
        float bn = bias[n];
        #pragma unroll
        for (int r = 0; r < 4; r++){
            int rowg = m0 + g * 4 + r;
            if (rowg < NN){
                float v = acc[nt][r] + bn;
                out[rowg * 256 + n] = f2b(v > 0.f ? v : 0.f);
            }
        }
    }
}

// ---------------- node-level P GEMM: P[:, 0:256]=h@W1a (+b1+td*w513 baked), P[:, 256:512]=h@W1b ----------------
// grid (313, 4), 256 threads: block = 64 nodes x 128 cols of the 512-col [Pa|Pb] matrix. f32 output.
__global__ __launch_bounds__(256) void k_gemm_p(const u16* __restrict__ hin,
    const u16* __restrict__ Bc, const float* __restrict__ b1, const float* __restrict__ W1tail,
    const float* __restrict__ tdp, float* __restrict__ P){
    __shared__ __align__(16) u16 ldsB[4096];   // 8 KB: one k32-chunk, 8 local ntiles
    int t = threadIdx.x, wave = t >> 6, lane = t & 63;
    int m0 = blockIdx.x * 64 + wave * 16;
    int nb = blockIdx.y * 8;                   // global ntile base (0..31 total)
    int ml = lane & 15, g = lane >> 4;
    int arow = m0 + ml; if (arow > NN - 1) arow = NN - 1;
    const u16* ph = hin + arow * 256;
    float td = tdp[0];

    int flat0 = t * 8, flat1 = (256 + t) * 8;
    int s0i = flat0 >> 9, o0 = flat0 & 511;
    int s1i = flat1 >> 9, o1 = flat1 & 511;
    uint4 p0 = *(const uint4*)(Bc + ((nb + s0i) * 8 + 0) * 512 + o0);
    uint4 p1 = *(const uint4*)(Bc + ((nb + s1i) * 8 + 0) * 512 + o1);

    f32x4 acc[8] = {};
    for (int k32 = 0; k32 < 8; k32++){
        __syncthreads();
        *(uint4*)(&ldsB[s0i * 512 + o0]) = p0;
        *(uint4*)(&ldsB[s1i * 512 + o1]) = p1;
        if (k32 < 7){
            p0 = *(const uint4*)(Bc + ((nb + s0i) * 8 + k32 + 1) * 512 + o0);
            p1 = *(const uint4*)(Bc + ((nb + s1i) * 8 + k32 + 1) * 512 + o1);
        }
        __syncthreads();
        bf16x8 af = __builtin_bit_cast(bf16x8, *(const uint4*)(ph + k32 * 32 + g * 8));
        #pragma unroll
        for (int nt = 0; nt < 8; nt++){
            bf16x8 bfr = __builtin_bit_cast(bf16x8, *(const uint4*)(&ldsB[(nt * 64 + lane) * 8]));
            acc[nt] = __builtin_amdgcn_mfma_f32_16x16x32_bf16(af, bfr, acc[nt], 0, 0, 0);
        }
    }
    #pragma unroll
    for (int nt = 0; nt < 8; nt++){
        int n = (nb + nt) * 16 + ml;                       // 0..511
        float base = (n < 256) ? (b1[n] + td * W1tail[256 + n]) : 0.f;
        #pragma unroll
        for (int r = 0; r < 4; r++){
            int rowg = m0 + g * 4 + r;
            if (rowg < NN) P[(size_t)rowg * 512 + n] = acc[nt][r] + base;
        }
    }
}

// ---------------- edge kernel: z1 = relu(Pa[row]+Pb[col]+ea*w512) -> GEMM2 -> W3 dot ----------------
// 512 threads, 128 edges/block. Phase A: f32 row gather+add+relu, bf16 pack into swizzled ldsZ
// (wave-local). Phase B: round-0 GEMM2 (staged 8KB B2 chunks) + W3 epilogue.
__global__ __launch_bounds__(512) void k_edge(const float* __restrict__ P,
    const int* __restrict__ rowp, const int* __restrict__ colp, const float* __restrict__ ea,
    const float* __restrict__ W1tail,
    const u16* __restrict__ B2s, const float* __restrict__ b2v,
    const float* __restrict__ W3, const float* __restrict__ b3, float* __restrict__ out){
    __shared__ __align__(16) u16 ldsX[4096];    // 8 KB: one B2 k32-chunk
    __shared__ __align__(16) u16 ldsZ[32768];   // 64 KB: z1, per-wave 16 x 256, xor-swizzled
    int t = threadIdx.x, wave = t >> 6, lane = t & 63;
    int m0 = blockIdx.x * 128;
    int half = lane >> 5, cl = lane & 31;
    int c0 = cl * 8;

    float wv[8];
    #pragma unroll
    for (int j = 0; j < 8; j++) wv[j] = W1tail[c0 + j];   // w512 chunk, fixed per lane

    // phase A: wave's 16 edges, 2 in flight (one per 32-lane half)
    for (int it = 0; it < 8; it++){
        int r = it * 2 + half;                 // local edge row 0..15
        int e = m0 + wave * 16 + r; if (e > NE - 1) e = NE - 1;
        const float* pa = P + (size_t)rowp[e] * 512;          // Pa row (bias baked)
        const float* pb = P + (size_t)colp[e] * 512 + 256;    // Pb row
        float eav = ea[e];
        float4 A0 = *(const float4*)(pa + c0);
        float4 A1 = *(const float4*)(pa + c0 + 4);
        float4 B0 = *(const float4*)(pb + c0);
        float4 B1 = *(const float4*)(pb + c0 + 4);
        float v0 = A0.x + B0.x + eav * wv[0];
        float v1 = A0.y + B0.y + eav * wv[1];
        float v2 = A0.z + B0.z + eav * wv[2];
        float v3 = A0.w + B0.w + eav * wv[3];
        float v4 = A1.x + B1.x + eav * wv[4];
        float v5 = A1.y + B1.y + eav * wv[5];
        float v6 = A1.z + B1.z + eav * wv[6];
        float v7 = A1.w + B1.w + eav * wv[7];
        v0 = v0 > 0.f ? v0 : 0.f; v1 = v1 > 0.f ? v1 : 0.f;
        v2 = v2 > 0.f ? v2 : 0.f; v3 = v3 > 0.f ? v3 : 0.f;
        v4 = v4 > 0.f ? v4 : 0.f; v5 = v5 > 0.f ? v5 : 0.f;
        v6 = v6 > 0.f ? v6 : 0.f; v7 = v7 > 0.f ? v7 : 0.f;
        uint4 st;
        st.x = (u32)f2b(v0) | ((u32)f2b(v1) << 16);
        st.y = (u32)f2b(v2) | ((u32)f2b(v3) << 16);
        st.z = (u32)f2b(v4) | ((u32)f2b(v5) << 16);
        st.w = (u32)f2b(v6) | ((u32)f2b(v7) << 16);
        *(uint4*)(&ldsZ[wave * 4096 + r * 256 + ((cl ^ (r & 7)) << 3)]) = st;
    }
    // no cross-wave ldsZ dependency (wave reads only its own slice); barriers below cover ldsX

    int ml = lane & 15, g = lane >> 4;
    int nt0 = t >> 6, off0 = (t & 63) * 8;
    f32x4 acc2[8] = {};
    uint4 q0 = *(const uint4*)(B2s + (nt0 * 8 + 0) * 512 + off0);
    for (int kc = 0; kc < 8; kc++){
        __syncthreads();
        *(uint4*)(&ldsX[nt0 * 512 + off0]) = q0;
        if (kc < 7) q0 = *(const uint4*)(B2s + (nt0 * 8 + kc + 1) * 512 + off0);
        __syncthreads();
        int kb = kc * 4 + g;
        bf16x8 af = __builtin_bit_cast(bf16x8, *(const uint4*)(&ldsZ[wave * 4096 + ml * 256 + ((kb ^ (ml & 7)) << 3)]));
        #pragma unroll
        for (int nt = 0; nt < 8; nt++){
            bf16x8 bfr = __builtin_bit_cast(bf16x8, *(const uint4*)(&ldsX[(nt * 64 + lane) * 8]));
            acc2[nt] = __builtin_amdgcn_mfma_f32_16x16x32_bf16(af, bfr, acc2[nt], 0, 0, 0);
        }
    }
    float s0 = 0.f, s1 = 0.f, s2 = 0.f, s3 = 0.f;
    #pragma unroll
    for (int nt = 0; nt < 8; nt++){
        int n = nt * 16 + ml;
        float bn = b2v[n];
        float w3 = W3[n];
        float z;
        z = acc2[nt][0] + bn; s0 += (z > 0.f ? z : 0.f) * w3;
        z = acc2[nt][1] + bn; s1 += (z > 0.f ? z : 0.f) * w3;
        z = acc2[nt][2] + bn; s2 += (z > 0.f ? z : 0.f) * w3;
        z = acc2[nt][3] + bn; s3 += (z > 0.f ? z : 0.f) * w3;
    }
    #pragma unroll
    for (int d = 1; d < 16; d <<= 1){
        s0 += __shfl_xor(s0, d); s1 += __shfl_xor(s1, d);
        s2 += __shfl_xor(s2, d); s3 += __shfl_xor(s3, d);
    }
    if (ml == 0){
        float bb = b3[0];
        int eb = m0 + wave * 16 + g * 4;
        if (eb + 0 < NE) out[eb + 0] = s0 + bb;
        if (eb + 1 < NE) out[eb + 1] = s1 + bb;
        if (eb + 2 < NE) out[eb + 2] = s2 + bb;
        if (eb + 3 < NE) out[eb + 3] = s3 + bb;
    }
}

__global__ void k_fillcode_f32(float* __restrict__ out, float c){
    int i = blockIdx.x * 256 + threadIdx.x;
    if (i < NE) out[i] = c;
}

extern "C" void kernel_launch(void* const* d_in, const int* in_sizes, int n_in,
                              void* d_out, int out_size, void* d_ws, size_t ws_size,
                              hipStream_t stream){
    float* out = (float*)d_out;

    static const int exp_sizes[19] = {60000,600000,300000,1,768,256,768,65536,256,65536,
                                      65536,256,65536,131584,256,32768,128,128,1};
    int bad = -1;
    if (n_in != 19) bad = 19;
    else for (int k = 0; k < 19; k++) if (in_sizes[k] != exp_sizes[k]){ bad = k; break; }
    if (bad >= 0){
        k_fillcode_f32<<<(NE + 255) / 256, 256, 0, stream>>>(out, 1000.f + 50.f * bad);
        return;
    }

    char* ws = (char*)d_ws;
    size_t off = 0;
    auto alloc = [&](size_t bytes) -> void* {
        void* p = ws + off;
        off += (bytes + 255) & ~(size_t)255;
        return p;
    };
    int*   deg   = (int*)alloc(NN * 4);
    int*   cur   = (int*)alloc(NN * 4);
    int*   offs  = (int*)alloc((NN + 1) * 4);
    float* invd  = (float*)alloc(NN * 4);
    int*   srcs  = (int*)alloc(NE * 4);
    u16*   h1b   = (u16*)alloc((size_t)NN * 256 * 2);
    u16*   h2b   = (u16*)alloc((size_t)NN * 256 * 2);
    u16*   h3b   = (u16*)alloc((size_t)NN * 256 * 2);
    u16*   aggb  = (u16*)alloc((size_t)NN * 256 * 2);
    u16*   WLs2  = (u16*)alloc(512 * 256 * 2);
    u16*   WLs3  = (u16*)alloc(512 * 256 * 2);
    u16*   Bcat  = (u16*)alloc(512 * 256 * 2);          // [W1a|W1b] cat fragments (256K x... 131072 u16)
    u16*   B2s   = (u16*)alloc(256 * 128 * 2);
    float* Pbuf  = (float*)alloc((size_t)NN * 512 * 4); // 41 MB: [Pa|Pb] f32
    if (off > ws_size){
        k_fillcode_f32<<<(NE + 255) / 256, 256, 0, stream>>>(out, 9000.f);
        return;
    }

    const float* x   = (const float*)d_in[0];
    const int*   ei  = (const int*)d_in[1];     // (2,E) int32: [row..., col...]
    const float* ea  = (const float*)d_in[2];
    const float* td  = (const float*)d_in[3];
    const float* Wl1 = (const float*)d_in[4];
    const float* bl1 = (const float*)d_in[5];
    const float* Wr1 = (const float*)d_in[6];
    const float* Wl2 = (const float*)d_in[7];
    const float* bl2 = (const float*)d_in[8];
    const float* Wr2 = (const float*)d_in[9];
    const float* Wl3 = (const float*)d_in[10];
    const float* bl3 = (const float*)d_in[11];
    const float* Wr3 = (const float*)d_in[12];
    const float* W1  = (const float*)d_in[13];
    const float* b1  = (const float*)d_in[14];
    const float* W2  = (const float*)d_in[15];
    const float* b2  = (const float*)d_in[16];
    const float* W3  = (const float*)d_in[17];
    const float* b3  = (const float*)d_in[18];

    hipMemsetAsync(deg, 0, (size_t)((char*)cur - (char*)deg) + NN * 4, stream);

    const int* rowv = ei;          // sources
    const int* colv = ei + NE;     // targets

    k_count<<<(NE + 255) / 256, 256, 0, stream>>>(colv, deg);
    k_scan <<<1, 1024, 0, stream>>>(deg, offs, invd);
    k_fill <<<(NE + 255) / 256, 256, 0, stream>>>(rowv, colv, offs, cur, srcs);

    // weight fragment prep
    k_swz_pair_f32<<<512, 256, 0, stream>>>(Wl2, Wr2, WLs2, 256, 256, 16);
    k_swz_pair_f32<<<512, 256, 0, stream>>>(Wl3, Wr3, WLs3, 256, 256, 16);
    k_swz_cat<<<512, 256, 0, stream>>>(W1, Bcat);
    k_swz_f32<<<128, 256, 0, stream>>>(W2, B2s, 128, 8);

    // SAGE layer 1 (fp32 math, bf16 out)
    k_layer1<<<NN / 4, 256, 0, stream>>>(x, offs, srcs, invd, Wl1, bl1, Wr1, h1b);

    dim3 ggrid((NN + 63) / 64, 2);

    // SAGE layers 2,3: separate aggr (high TLP) + N-split staged GEMM
    k_aggr<<<NN / 4, 256, 0, stream>>>(h1b, offs, srcs, invd, aggb);
    k_gemm_node<<<ggrid, 256, 0, stream>>>(aggb, h1b, WLs2, bl2, h2b);

    k_aggr<<<NN / 4, 256, 0, stream>>>(h2b, offs, srcs, invd, aggb);
    k_gemm_node<<<ggrid, 256, 0, stream>>>(aggb, h2b, WLs3, bl3, h3b);

    // node-level P = h3 @ [W1a|W1b] (f32, bias+td baked into Pa cols)
    dim3 pgrid((NN + 63) / 64, 4);
    k_gemm_p<<<pgrid, 256, 0, stream>>>(h3b, Bcat, b1, W1 + 512 * 256, td, Pbuf);

    // edge kernel: gather Pa[row]+Pb[col], relu -> GEMM2 -> W3 dot
    k_edge<<<(NE + 127) / 128, 512, 0, stream>>>(Pbuf, rowv, colv, ea, W1 + 512 * 256,
                                                 B2s, b2, W3, b3, out);
}

// Round 6
// 380.077 us; speedup vs baseline: 1.1555x; 1.0593x over previous
//
#include <hip/hip_runtime.h>

#define NN 20000
#define NE 300000

typedef unsigned short u16;
typedef unsigned int   u32;

typedef __bf16 bf16x8 __attribute__((ext_vector_type(8)));
typedef float  f32x4  __attribute__((ext_vector_type(4)));

__device__ __forceinline__ float b2f(u16 u){ u32 x = ((u32)u) << 16; return __builtin_bit_cast(float, x); }
__device__ __forceinline__ u16 f2b(float f){
    u32 x = __builtin_bit_cast(u32, f);
    u32 r = x + 0x7fffu + ((x >> 16) & 1u);
    return (u16)(r >> 16);
}

// ---------------- CSR build: bucket edges by col (target), store row (source) + col + orig id ----------------
__global__ void k_count(const int* __restrict__ key, int* __restrict__ deg){
    int e = blockIdx.x * 256 + threadIdx.x;
    if (e < NE){
        int c = key[e];
        if (c >= 0 && c < NN) atomicAdd(&deg[c], 1);
    }
}

__global__ void k_scan(const int* __restrict__ deg, int* __restrict__ offs, float* __restrict__ invd){
    __shared__ int part[1024];
    int t = threadIdx.x;
    int base = t * 20;
    int s = 0;
    for (int i = 0; i < 20; i++){ int idx = base + i; if (idx < NN) s += deg[idx]; }
    part[t] = s; __syncthreads();
    for (int d = 1; d < 1024; d <<= 1){
        int v = (t >= d) ? part[t - d] : 0;
        __syncthreads();
        part[t] += v;
        __syncthreads();
    }
    int run = part[t] - s;
    for (int i = 0; i < 20; i++){
        int idx = base + i;
        if (idx < NN){
            offs[idx] = run;
            int d0 = deg[idx];
            run += d0;
            invd[idx] = 1.0f / (float)(d0 > 0 ? d0 : 1);
        }
    }
    if (t == 1023) offs[NN] = part[1023];
}

__global__ void k_fill(const int* __restrict__ val, const int* __restrict__ key,
                       const int* __restrict__ offs, int* __restrict__ cur,
                       int* __restrict__ srcs, int* __restrict__ ecol, int* __restrict__ eid){
    int e = blockIdx.x * 256 + threadIdx.x;
    if (e < NE){
        int c = key[e];
        if (c >= 0 && c < NN){
            int slot = offs[c] + atomicAdd(&cur[c], 1);
            int r = val[e];
            srcs[slot] = (r >= 0 && r < NN) ? r : 0;
            ecol[slot] = c;
            eid[slot]  = e;
        }
    }
}

// ---------------- weight swizzle fp32 -> bf16 MFMA B-fragments ----------------
__global__ void k_swz_f32(const float* __restrict__ W, u16* __restrict__ dst, int N, int KT){
    int t = blockIdx.x * 256 + threadIdx.x;
    int j = t & 7, lane = (t >> 3) & 63, tile = t >> 9;
    int ktile = tile % KT, ntile = tile / KT;
    int k = ktile * 32 + ((lane >> 4) << 3) + j;
    int n = ntile * 16 + (lane & 15);
    dst[t] = f2b(W[k * N + n]);
}

__global__ void k_swz_pair_f32(const float* __restrict__ A, const float* __restrict__ B, u16* __restrict__ dst,
                               int halfK, int N, int KT){
    int t = blockIdx.x * 256 + threadIdx.x;
    int j = t & 7, lane = (t >> 3) & 63, tile = t >> 9;
    int ktile = tile % KT, ntile = tile / KT;
    int k = ktile * 32 + ((lane >> 4) << 3) + j;
    int n = ntile * 16 + (lane & 15);
    dst[t] = f2b((k < halfK) ? A[k * N + n] : B[(k - halfK) * N + n]);
}

// cat-swizzle for node-level P GEMM: B_cat[k][n'] = n'<256 ? W1[k][n'] : W1[256+k][n'-256]
__global__ void k_swz_cat(const float* __restrict__ W1, u16* __restrict__ dst){
    int t = blockIdx.x * 256 + threadIdx.x;       // 512 blocks x 256 = 131072
    int j = t & 7, lane = (t >> 3) & 63, tile = t >> 9;
    int ktile = tile & 7, ntile = tile >> 3;
    int k = ktile * 32 + ((lane >> 4) << 3) + j;  // 0..255
    int n = ntile * 16 + (lane & 15);             // 0..511
    float v = (n < 256) ? W1[k * 256 + n] : W1[(256 + k) * 256 + (n - 256)];
    dst[t] = f2b(v);
}

// ---------------- SAGE layer 1 (din=3): fp32 math, bf16 output ----------------
__global__ void k_layer1(const float* __restrict__ x, const int* __restrict__ offs, const int* __restrict__ srcs,
                         const float* __restrict__ invd, const float* __restrict__ Wl, const float* __restrict__ bl,
                         const float* __restrict__ Wr, u16* __restrict__ h1){
    int node = blockIdx.x * 4 + (threadIdx.x >> 6);
    int lane = threadIdx.x & 63;
    int st = offs[node], en = offs[node + 1];
    float s0 = 0.f, s1 = 0.f, s2 = 0.f;
    for (int j = st + lane; j < en; j += 64){
        int s = srcs[j];
        s0 += x[s * 3 + 0]; s1 += x[s * 3 + 1]; s2 += x[s * 3 + 2];
    }
    #pragma unroll
    for (int d = 1; d < 64; d <<= 1){
        s0 += __shfl_xor(s0, d); s1 += __shfl_xor(s1, d); s2 += __shfl_xor(s2, d);
    }
    float inv = invd[node];
    float a0 = s0 * inv, a1 = s1 * inv, a2 = s2 * inv;
    float xi0 = x[node * 3 + 0], xi1 = x[node * 3 + 1], xi2 = x[node * 3 + 2];
    int f0 = lane * 4;
    ushort4 stv;
    u16* sp = (u16*)&stv;
    #pragma unroll
    for (int r = 0; r < 4; r++){
        int n = f0 + r;
        float o = a0 * Wl[n] + a1 * Wl[256 + n] + a2 * Wl[512 + n]
                + xi0 * Wr[n] + xi1 * Wr[256 + n] + xi2 * Wr[512 + n] + bl[n];
        sp[r] = f2b(o > 0.f ? o : 0.f);
    }
    *(ushort4*)(h1 + node * 256 + f0) = stv;
}

// ---------------- mean aggregation over CSR: 16B/lane, 2 rows in flight per wave ----------------
__global__ void k_aggr(const u16* __restrict__ hin, const int* __restrict__ offs, const int* __restrict__ srcs,
                       const float* __restrict__ invd, u16* __restrict__ aggr){
    int node = blockIdx.x * 4 + (threadIdx.x >> 6);
    int lane = threadIdx.x & 63;
    int st = offs[node], en = offs[node + 1];
    int half = lane >> 5;
    int c0 = (lane & 31) * 8;
    float a0=0.f,a1=0.f,a2=0.f,a3=0.f,a4=0.f,a5=0.f,a6=0.f,a7=0.f;
    for (int j = st + half; j < en; j += 2){
        int s = srcs[j];
        uint4 v = *(const uint4*)(hin + s * 256 + c0);
        a0 += b2f((u16)v.x); a1 += b2f((u16)(v.x >> 16));
        a2 += b2f((u16)v.y); a3 += b2f((u16)(v.y >> 16));
        a4 += b2f((u16)v.z); a5 += b2f((u16)(v.z >> 16));
        a6 += b2f((u16)v.w); a7 += b2f((u16)(v.w >> 16));
    }
    a0 += __shfl_xor(a0, 32); a1 += __shfl_xor(a1, 32);
    a2 += __shfl_xor(a2, 32); a3 += __shfl_xor(a3, 32);
    a4 += __shfl_xor(a4, 32); a5 += __shfl_xor(a5, 32);
    a6 += __shfl_xor(a6, 32); a7 += __shfl_xor(a7, 32);
    if (half == 0){
        float inv = invd[node];
        uint4 o;
        o.x = (u32)f2b(a0 * inv) | ((u32)f2b(a1 * inv) << 16);
        o.y = (u32)f2b(a2 * inv) | ((u32)f2b(a3 * inv) << 16);
        o.z = (u32)f2b(a4 * inv) | ((u32)f2b(a5 * inv) << 16);
        o.w = (u32)f2b(a6 * inv) | ((u32)f2b(a7 * inv) << 16);
        *(uint4*)(aggr + node * 256 + c0) = o;
    }
}

// ---------------- node dense layer: relu([aggr|hin] @ Bs + bias), MFMA, N-split grid ----------------
__global__ __launch_bounds__(256) void k_gemm_node(const u16* __restrict__ aggr, const u16* __restrict__ hin,
    const u16* __restrict__ Bs, const float* __restrict__ bias, u16* __restrict__ out){
    __shared__ __align__(16) u16 ldsB[4096];   // 8 KB: one k32-chunk, 8 local ntiles
    int t = threadIdx.x, wave = t >> 6, lane = t & 63;
    int m0 = blockIdx.x * 64 + wave * 16;
    int nb = blockIdx.y * 8;                   // global ntile base (8 ntiles = 128 cols)
    int ml = lane & 15, g = lane >> 4;
    int arow = m0 + ml; if (arow > NN - 1) arow = NN - 1;
    const u16* pa = aggr + arow * 256;
    const u16* ph = hin  + arow * 256;

    int flat0 = t * 8, flat1 = (256 + t) * 8;
    int s0i = flat0 >> 9, o0 = flat0 & 511;    // local ntile 0..3
    int s1i = flat1 >> 9, o1 = flat1 & 511;    // local ntile 4..7
    uint4 p0 = *(const uint4*)(Bs + ((nb + s0i) * 16 + 0) * 512 + o0);
    uint4 p1 = *(const uint4*)(Bs + ((nb + s1i) * 16 + 0) * 512 + o1);

    f32x4 acc[8] = {};
    for (int k32 = 0; k32 < 16; k32++){
        __syncthreads();
        *(uint4*)(&ldsB[s0i * 512 + o0]) = p0;
        *(uint4*)(&ldsB[s1i * 512 + o1]) = p1;
        if (k32 < 15){
            p0 = *(const uint4*)(Bs + ((nb + s0i) * 16 + k32 + 1) * 512 + o0);
            p1 = *(const uint4*)(Bs + ((nb + s1i) * 16 + k32 + 1) * 512 + o1);
        }
        __syncthreads();
        const u16* asrc = (k32 < 8) ? (pa + k32 * 32) : (ph + (k32 - 8) * 32);
        bf16x8 af = __builtin_bit_cast(bf16x8, *(const uint4*)(asrc + g * 8));
        #pragma unroll
        for (int nt = 0; nt < 8; nt++){
            bf16x8 bfr = __builtin_bit_cast(bf16x8, *(const uint4*)(&ldsB[(nt * 64 + lane) * 8]));
            acc[nt] = __builtin_amdgcn_mfma_f32_16x16x32_bf16(af, bfr, acc[nt], 0, 0, 0);
        }
    }
    #pragma unroll
    for (int nt = 0; nt < 8; nt++){
        int n = (nb + nt) * 16 + ml;
        float bn = bias[n];
        #pragma unroll
        for (int r = 0; r < 4; r++){
            int rowg = m0 + g * 4 + r;
            if (rowg < NN){
                float v = acc[nt][r] + bn;
                out[rowg * 256 + n] = f2b(v > 0.f ? v : 0.f);
            }
        }
    }
}

// ---------------- node-level P GEMM: P[:, 0:256]=h@W1a (+b1+td*w513 baked), P[:, 256:512]=h@W1b ----------------
__global__ __launch_bounds__(256) void k_gemm_p(const u16* __restrict__ hin,
    const u16* __restrict__ Bc, const float* __restrict__ b1, const float* __restrict__ W1tail,
    const float* __restrict__ tdp, float* __restrict__ P){
    __shared__ __align__(16) u16 ldsB[4096];   // 8 KB: one k32-chunk, 8 local ntiles
    int t = threadIdx.x, wave = t >> 6, lane = t & 63;
    int m0 = blockIdx.x * 64 + wave * 16;
    int nb = blockIdx.y * 8;                   // global ntile base (0..31 total)
    int ml = lane & 15, g = lane >> 4;
    int arow = m0 + ml; if (arow > NN - 1) arow = NN - 1;
    const u16* ph = hin + arow * 256;
    float td = tdp[0];

    int flat0 = t * 8, flat1 = (256 + t) * 8;
    int s0i = flat0 >> 9, o0 = flat0 & 511;
    int s1i = flat1 >> 9, o1 = flat1 & 511;
    uint4 p0 = *(const uint4*)(Bc + ((nb + s0i) * 8 + 0) * 512 + o0);
    uint4 p1 = *(const uint4*)(Bc + ((nb + s1i) * 8 + 0) * 512 + o1);

    f32x4 acc[8] = {};
    for (int k32 = 0; k32 < 8; k32++){
        __syncthreads();
        *(uint4*)(&ldsB[s0i * 512 + o0]) = p0;
        *(uint4*)(&ldsB[s1i * 512 + o1]) = p1;
        if (k32 < 7){
            p0 = *(const uint4*)(Bc + ((nb + s0i) * 8 + k32 + 1) * 512 + o0);
            p1 = *(const uint4*)(Bc + ((nb + s1i) * 8 + k32 + 1) * 512 + o1);
        }
        __syncthreads();
        bf16x8 af = __builtin_bit_cast(bf16x8, *(const uint4*)(ph + k32 * 32 + g * 8));
        #pragma unroll
        for (int nt = 0; nt < 8; nt++){
            bf16x8 bfr = __builtin_bit_cast(bf16x8, *(const uint4*)(&ldsB[(nt * 64 + lane) * 8]));
            acc[nt] = __builtin_amdgcn_mfma_f32_16x16x32_bf16(af, bfr, acc[nt], 0, 0, 0);
        }
    }
    #pragma unroll
    for (int nt = 0; nt < 8; nt++){
        int n = (nb + nt) * 16 + ml;                       // 0..511
        float base = (n < 256) ? (b1[n] + td * W1tail[256 + n]) : 0.f;
        #pragma unroll
        for (int r = 0; r < 4; r++){
            int rowg = m0 + g * 4 + r;
            if (rowg < NN) P[(size_t)rowg * 512 + n] = acc[nt][r] + base;
        }
    }
}

// ---------------- edge kernel (CSR-ordered): z1 = relu(Pa[src]+Pb[col]+ea*w512) -> GEMM2 -> W3 dot ----------------
// Edges processed in CSR slot order: consecutive slots share col -> Pb[col] L1/L2-hits.
// Outputs scattered to out[eid[slot]].
__global__ __launch_bounds__(512) void k_edge(const float* __restrict__ P,
    const int* __restrict__ srcs, const int* __restrict__ ecol, const int* __restrict__ eid,
    const float* __restrict__ ea, const float* __restrict__ W1tail,
    const u16* __restrict__ B2s, const float* __restrict__ b2v,
    const float* __restrict__ W3, const float* __restrict__ b3, float* __restrict__ out){
    __shared__ __align__(16) u16 ldsX[4096];    // 8 KB: one B2 k32-chunk
    __shared__ __align__(16) u16 ldsZ[32768];   // 64 KB: z1, per-wave 16 x 256, xor-swizzled
    int t = threadIdx.x, wave = t >> 6, lane = t & 63;
    int m0 = blockIdx.x * 128;
    int half = lane >> 5, cl = lane & 31;
    int c0 = cl * 8;

    float wv[8];
    #pragma unroll
    for (int j = 0; j < 8; j++) wv[j] = W1tail[c0 + j];   // w512 chunk, fixed per lane

    // phase A: wave's 16 CSR slots, 2 in flight (one per 32-lane half)
    for (int it = 0; it < 8; it++){
        int r = it * 2 + half;                 // local slot row 0..15
        int s = m0 + wave * 16 + r; if (s > NE - 1) s = NE - 1;
        const float* pa = P + (size_t)srcs[s] * 512;          // Pa row (bias baked)
        const float* pb = P + (size_t)ecol[s] * 512 + 256;    // Pb row (CSR-clustered -> cache hits)
        float eav = ea[eid[s]];
        float4 A0 = *(const float4*)(pa + c0);
        float4 A1 = *(const float4*)(pa + c0 + 4);
        float4 B0 = *(const float4*)(pb + c0);
        float4 B1 = *(const float4*)(pb + c0 + 4);
        float v0 = A0.x + B0.x + eav * wv[0];
        float v1 = A0.y + B0.y + eav * wv[1];
        float v2 = A0.z + B0.z + eav * wv[2];
        float v3 = A0.w + B0.w + eav * wv[3];
        float v4 = A1.x + B1.x + eav * wv[4];
        float v5 = A1.y + B1.y + eav * wv[5];
        float v6 = A1.z + B1.z + eav * wv[6];
        float v7 = A1.w + B1.w + eav * wv[7];
        v0 = v0 > 0.f ? v0 : 0.f; v1 = v1 > 0.f ? v1 : 0.f;
        v2 = v2 > 0.f ? v2 : 0.f; v3 = v3 > 0.f ? v3 : 0.f;
        v4 = v4 > 0.f ? v4 : 0.f; v5 = v5 > 0.f ? v5 : 0.f;
        v6 = v6 > 0.f ? v6 : 0.f; v7 = v7 > 0.f ? v7 : 0.f;
        uint4 st;
        st.x = (u32)f2b(v0) | ((u32)f2b(v1) << 16);
        st.y = (u32)f2b(v2) | ((u32)f2b(v3) << 16);
        st.z = (u32)f2b(v4) | ((u32)f2b(v5) << 16);
        st.w = (u32)f2b(v6) | ((u32)f2b(v7) << 16);
        *(uint4*)(&ldsZ[wave * 4096 + r * 256 + ((cl ^ (r & 7)) << 3)]) = st;
    }
    // no cross-wave ldsZ dependency (wave reads only its own slice); barriers below cover ldsX

    int ml = lane & 15, g = lane >> 4;
    int nt0 = t >> 6, off0 = (t & 63) * 8;
    f32x4 acc2[8] = {};
    uint4 q0 = *(const uint4*)(B2s + (nt0 * 8 + 0) * 512 + off0);
    for (int kc = 0; kc < 8; kc++){
        __syncthreads();
        *(uint4*)(&ldsX[nt0 * 512 + off0]) = q0;
        if (kc < 7) q0 = *(const uint4*)(B2s + (nt0 * 8 + kc + 1) * 512 + off0);
        __syncthreads();
        int kb = kc * 4 + g;
        bf16x8 af = __builtin_bit_cast(bf16x8, *(const uint4*)(&ldsZ[wave * 4096 + ml * 256 + ((kb ^ (ml & 7)) << 3)]));
        #pragma unroll
        for (int nt = 0; nt < 8; nt++){
            bf16x8 bfr = __builtin_bit_cast(bf16x8, *(const uint4*)(&ldsX[(nt * 64 + lane) * 8]));
            acc2[nt] = __builtin_amdgcn_mfma_f32_16x16x32_bf16(af, bfr, acc2[nt], 0, 0, 0);
        }
    }
    float s0 = 0.f, s1 = 0.f, s2 = 0.f, s3 = 0.f;
    #pragma unroll
    for (int nt = 0; nt < 8; nt++){
        int n = nt * 16 + ml;
        float bn = b2v[n];
        float w3 = W3[n];
        float z;
        z = acc2[nt][0] + bn; s0 += (z > 0.f ? z : 0.f) * w3;
        z = acc2[nt][1] + bn; s1 += (z > 0.f ? z : 0.f) * w3;
        z = acc2[nt][2] + bn; s2 += (z > 0.f ? z : 0.f) * w3;
        z = acc2[nt][3] + bn; s3 += (z > 0.f ? z : 0.f) * w3;
    }
    #pragma unroll
    for (int d = 1; d < 16; d <<= 1){
        s0 += __shfl_xor(s0, d); s1 += __shfl_xor(s1, d);
        s2 += __shfl_xor(s2, d); s3 += __shfl_xor(s3, d);
    }
    if (ml == 0){
        float bb = b3[0];
        int sb = m0 + wave * 16 + g * 4;
        if (sb + 0 < NE) out[eid[sb + 0]] = s0 + bb;
        if (sb + 1 < NE) out[eid[sb + 1]] = s1 + bb;
        if (sb + 2 < NE) out[eid[sb + 2]] = s2 + bb;
        if (sb + 3 < NE) out[eid[sb + 3]] = s3 + bb;
    }
}

__global__ void k_fillcode_f32(float* __restrict__ out, float c){
    int i = blockIdx.x * 256 + threadIdx.x;
    if (i < NE) out[i] = c;
}

extern "C" void kernel_launch(void* const* d_in, const int* in_sizes, int n_in,
                              void* d_out, int out_size, void* d_ws, size_t ws_size,
                              hipStream_t stream){
    float* out = (float*)d_out;

    static const int exp_sizes[19] = {60000,600000,300000,1,768,256,768,65536,256,65536,
                                      65536,256,65536,131584,256,32768,128,128,1};
    int bad = -1;
    if (n_in != 19) bad = 19;
    else for (int k = 0; k < 19; k++) if (in_sizes[k] != exp_sizes[k]){ bad = k; break; }
    if (bad >= 0){
        k_fillcode_f32<<<(NE + 255) / 256, 256, 0, stream>>>(out, 1000.f + 50.f * bad);
        return;
    }

    char* ws = (char*)d_ws;
    size_t off = 0;
    auto alloc = [&](size_t bytes) -> void* {
        void* p = ws + off;
        off += (bytes + 255) & ~(size_t)255;
        return p;
    };
    int*   deg   = (int*)alloc(NN * 4);
    int*   cur   = (int*)alloc(NN * 4);
    int*   offs  = (int*)alloc((NN + 1) * 4);
    float* invd  = (float*)alloc(NN * 4);
    int*   srcs  = (int*)alloc(NE * 4);
    int*   ecol  = (int*)alloc(NE * 4);
    int*   eidb  = (int*)alloc(NE * 4);
    u16*   h1b   = (u16*)alloc((size_t)NN * 256 * 2);
    u16*   h2b   = (u16*)alloc((size_t)NN * 256 * 2);
    u16*   h3b   = (u16*)alloc((size_t)NN * 256 * 2);
    u16*   aggb  = (u16*)alloc((size_t)NN * 256 * 2);
    u16*   WLs2  = (u16*)alloc(512 * 256 * 2);
    u16*   WLs3  = (u16*)alloc(512 * 256 * 2);
    u16*   Bcat  = (u16*)alloc(512 * 256 * 2);          // [W1a|W1b] cat fragments
    u16*   B2s   = (u16*)alloc(256 * 128 * 2);
    float* Pbuf  = (float*)alloc((size_t)NN * 512 * 4); // 41 MB: [Pa|Pb] f32
    if (off > ws_size){
        k_fillcode_f32<<<(NE + 255) / 256, 256, 0, stream>>>(out, 9000.f);
        return;
    }

    const float* x   = (const float*)d_in[0];
    const int*   ei  = (const int*)d_in[1];     // (2,E) int32: [row..., col...]
    const float* ea  = (const float*)d_in[2];
    const float* td  = (const float*)d_in[3];
    const float* Wl1 = (const float*)d_in[4];
    const float* bl1 = (const float*)d_in[5];
    const float* Wr1 = (const float*)d_in[6];
    const float* Wl2 = (const float*)d_in[7];
    const float* bl2 = (const float*)d_in[8];
    const float* Wr2 = (const float*)d_in[9];
    const float* Wl3 = (const float*)d_in[10];
    const float* bl3 = (const float*)d_in[11];
    const float* Wr3 = (const float*)d_in[12];
    const float* W1  = (const float*)d_in[13];
    const float* b1  = (const float*)d_in[14];
    const float* W2  = (const float*)d_in[15];
    const float* b2  = (const float*)d_in[16];
    const float* W3  = (const float*)d_in[17];
    const float* b3  = (const float*)d_in[18];

    hipMemsetAsync(deg, 0, (size_t)((char*)cur - (char*)deg) + NN * 4, stream);

    const int* rowv = ei;          // sources
    const int* colv = ei + NE;     // targets

    k_count<<<(NE + 255) / 256, 256, 0, stream>>>(colv, deg);
    k_scan <<<1, 1024, 0, stream>>>(deg, offs, invd);
    k_fill <<<(NE + 255) / 256, 256, 0, stream>>>(rowv, colv, offs, cur, srcs, ecol, eidb);

    // weight fragment prep
    k_swz_pair_f32<<<512, 256, 0, stream>>>(Wl2, Wr2, WLs2, 256, 256, 16);
    k_swz_pair_f32<<<512, 256, 0, stream>>>(Wl3, Wr3, WLs3, 256, 256, 16);
    k_swz_cat<<<512, 256, 0, stream>>>(W1, Bcat);
    k_swz_f32<<<128, 256, 0, stream>>>(W2, B2s, 128, 8);

    // SAGE layer 1 (fp32 math, bf16 out)
    k_layer1<<<NN / 4, 256, 0, stream>>>(x, offs, srcs, invd, Wl1, bl1, Wr1, h1b);

    dim3 ggrid((NN + 63) / 64, 2);

    // SAGE layers 2,3: separate aggr (high TLP) + N-split staged GEMM
    k_aggr<<<NN / 4, 256, 0, stream>>>(h1b, offs, srcs, invd, aggb);
    k_gemm_node<<<ggrid, 256, 0, stream>>>(aggb, h1b, WLs2, bl2, h2b);

    k_aggr<<<NN / 4, 256, 0, stream>>>(h2b, offs, srcs, invd, aggb);
    k_gemm_node<<<ggrid, 256, 0, stream>>>(aggb, h2b, WLs3, bl3, h3b);

    // node-level P = h3 @ [W1a|W1b] (f32, bias+td baked into Pa cols)
    dim3 pgrid((NN + 63) / 64, 4);
    k_gemm_p<<<pgrid, 256, 0, stream>>>(h3b, Bcat, b1, W1 + 512 * 256, td, Pbuf);

    // edge kernel (CSR order): gather Pa[src] (random) + Pb[col] (clustered), relu -> GEMM2 -> W3 dot
    k_edge<<<(NE + 127) / 128, 512, 0, stream>>>(Pbuf, srcs, ecol, eidb, ea, W1 + 512 * 256,
                                                 B2s, b2, W3, b3, out);
}

// Round 7
// 355.831 us; speedup vs baseline: 1.2342x; 1.0681x over previous
//
#include <hip/hip_runtime.h>

#define NN 20000
#define NE 300000

typedef unsigned short u16;
typedef unsigned int   u32;

typedef __bf16 bf16x8 __attribute__((ext_vector_type(8)));
typedef float  f32x4  __attribute__((ext_vector_type(4)));

__device__ __forceinline__ float b2f(u16 u){ u32 x = ((u32)u) << 16; return __builtin_bit_cast(float, x); }
__device__ __forceinline__ u16 f2b(float f){
    u32 x = __builtin_bit_cast(u32, f);
    u32 r = x + 0x7fffu + ((x >> 16) & 1u);
    return (u16)(r >> 16);
}

// ---------------- CSR build: bucket edges by col (target) ----------------
__global__ void k_count(const int* __restrict__ key, int* __restrict__ deg){
    int e = blockIdx.x * 256 + threadIdx.x;
    if (e < NE){
        int c = key[e];
        if (c >= 0 && c < NN) atomicAdd(&deg[c], 1);
    }
}

__global__ void k_scan(const int* __restrict__ deg, int* __restrict__ offs, float* __restrict__ invd){
    __shared__ int part[1024];
    int t = threadIdx.x;
    int base = t * 20;
    int s = 0;
    for (int i = 0; i < 20; i++){ int idx = base + i; if (idx < NN) s += deg[idx]; }
    part[t] = s; __syncthreads();
    for (int d = 1; d < 1024; d <<= 1){
        int v = (t >= d) ? part[t - d] : 0;
        __syncthreads();
        part[t] += v;
        __syncthreads();
    }
    int run = part[t] - s;
    for (int i = 0; i < 20; i++){
        int idx = base + i;
        if (idx < NN){
            offs[idx] = run;
            int d0 = deg[idx];
            run += d0;
            invd[idx] = 1.0f / (float)(d0 > 0 ? d0 : 1);
        }
    }
    if (t == 1023) offs[NN] = part[1023];
}

// fills srcs (for layer1/aggr) and meta int4 {src, col, orig edge id, ea bits} (for k_edge)
__global__ void k_fill(const int* __restrict__ val, const int* __restrict__ key,
                       const float* __restrict__ ea, const int* __restrict__ offs,
                       int* __restrict__ cur, int* __restrict__ srcs, int4* __restrict__ meta){
    int e = blockIdx.x * 256 + threadIdx.x;
    if (e < NE){
        int c = key[e];
        if (c >= 0 && c < NN){
            int slot = offs[c] + atomicAdd(&cur[c], 1);
            int r = val[e];
            int sv = (r >= 0 && r < NN) ? r : 0;
            srcs[slot] = sv;
            int4 m;
            m.x = sv;
            m.y = c;
            m.z = e;
            m.w = __builtin_bit_cast(int, ea[e]);
            meta[slot] = m;
        }
    }
}

// ---------------- weight swizzle fp32 -> bf16 MFMA B-fragments ----------------
__global__ void k_swz_f32(const float* __restrict__ W, u16* __restrict__ dst, int N, int KT){
    int t = blockIdx.x * 256 + threadIdx.x;
    int j = t & 7, lane = (t >> 3) & 63, tile = t >> 9;
    int ktile = tile % KT, ntile = tile / KT;
    int k = ktile * 32 + ((lane >> 4) << 3) + j;
    int n = ntile * 16 + (lane & 15);
    dst[t] = f2b(W[k * N + n]);
}

__global__ void k_swz_pair_f32(const float* __restrict__ A, const float* __restrict__ B, u16* __restrict__ dst,
                               int halfK, int N, int KT){
    int t = blockIdx.x * 256 + threadIdx.x;
    int j = t & 7, lane = (t >> 3) & 63, tile = t >> 9;
    int ktile = tile % KT, ntile = tile / KT;
    int k = ktile * 32 + ((lane >> 4) << 3) + j;
    int n = ntile * 16 + (lane & 15);
    dst[t] = f2b((k < halfK) ? A[k * N + n] : B[(k - halfK) * N + n]);
}

// cat-swizzle for node-level P GEMM: B_cat[k][n'] = n'<256 ? W1[k][n'] : W1[256+k][n'-256]
__global__ void k_swz_cat(const float* __restrict__ W1, u16* __restrict__ dst){
    int t = blockIdx.x * 256 + threadIdx.x;       // 512 blocks x 256 = 131072
    int j = t & 7, lane = (t >> 3) & 63, tile = t >> 9;
    int ktile = tile & 7, ntile = tile >> 3;
    int k = ktile * 32 + ((lane >> 4) << 3) + j;  // 0..255
    int n = ntile * 16 + (lane & 15);             // 0..511
    float v = (n < 256) ? W1[k * 256 + n] : W1[(256 + k) * 256 + (n - 256)];
    dst[t] = f2b(v);
}

// ---------------- SAGE layer 1 (din=3): fp32 math, bf16 output ----------------
__global__ void k_layer1(const float* __restrict__ x, const int* __restrict__ offs, const int* __restrict__ srcs,
                         const float* __restrict__ invd, const float* __restrict__ Wl, const float* __restrict__ bl,
                         const float* __restrict__ Wr, u16* __restrict__ h1){
    int node = blockIdx.x * 4 + (threadIdx.x >> 6);
    int lane = threadIdx.x & 63;
    int st = offs[node], en = offs[node + 1];
    float s0 = 0.f, s1 = 0.f, s2 = 0.f;
    for (int j = st + lane; j < en; j += 64){
        int s = srcs[j];
        s0 += x[s * 3 + 0]; s1 += x[s * 3 + 1]; s2 += x[s * 3 + 2];
    }
    #pragma unroll
    for (int d = 1; d < 64; d <<= 1){
        s0 += __shfl_xor(s0, d); s1 += __shfl_xor(s1, d); s2 += __shfl_xor(s2, d);
    }
    float inv = invd[node];
    float a0 = s0 * inv, a1 = s1 * inv, a2 = s2 * inv;
    float xi0 = x[node * 3 + 0], xi1 = x[node * 3 + 1], xi2 = x[node * 3 + 2];
    int f0 = lane * 4;
    ushort4 stv;
    u16* sp = (u16*)&stv;
    #pragma unroll
    for (int r = 0; r < 4; r++){
        int n = f0 + r;
        float o = a0 * Wl[n] + a1 * Wl[256 + n] + a2 * Wl[512 + n]
                + xi0 * Wr[n] + xi1 * Wr[256 + n] + xi2 * Wr[512 + n] + bl[n];
        sp[r] = f2b(o > 0.f ? o : 0.f);
    }
    *(ushort4*)(h1 + node * 256 + f0) = stv;
}

// ---------------- mean aggregation over CSR: 16B/lane, 2 rows in flight per wave ----------------
__global__ void k_aggr(const u16* __restrict__ hin, const int* __restrict__ offs, const int* __restrict__ srcs,
                       const float* __restrict__ invd, u16* __restrict__ aggr){
    int node = blockIdx.x * 4 + (threadIdx.x >> 6);
    int lane = threadIdx.x & 63;
    int st = offs[node], en = offs[node + 1];
    int half = lane >> 5;
    int c0 = (lane & 31) * 8;
    float a0=0.f,a1=0.f,a2=0.f,a3=0.f,a4=0.f,a5=0.f,a6=0.f,a7=0.f;
    for (int j = st + half; j < en; j += 2){
        int s = srcs[j];
        uint4 v = *(const uint4*)(hin + s * 256 + c0);
        a0 += b2f((u16)v.x); a1 += b2f((u16)(v.x >> 16));
        a2 += b2f((u16)v.y); a3 += b2f((u16)(v.y >> 16));
        a4 += b2f((u16)v.z); a5 += b2f((u16)(v.z >> 16));
        a6 += b2f((u16)v.w); a7 += b2f((u16)(v.w >> 16));
    }
    a0 += __shfl_xor(a0, 32); a1 += __shfl_xor(a1, 32);
    a2 += __shfl_xor(a2, 32); a3 += __shfl_xor(a3, 32);
    a4 += __shfl_xor(a4, 32); a5 += __shfl_xor(a5, 32);
    a6 += __shfl_xor(a6, 32); a7 += __shfl_xor(a7, 32);
    if (half == 0){
        float inv = invd[node];
        uint4 o;
        o.x = (u32)f2b(a0 * inv) | ((u32)f2b(a1 * inv) << 16);
        o.y = (u32)f2b(a2 * inv) | ((u32)f2b(a3 * inv) << 16);
        o.z = (u32)f2b(a4 * inv) | ((u32)f2b(a5 * inv) << 16);
        o.w = (u32)f2b(a6 * inv) | ((u32)f2b(a7 * inv) << 16);
        *(uint4*)(aggr + node * 256 + c0) = o;
    }
}

// ---------------- node dense layer: relu([aggr|hin] @ Bs + bias), MFMA, N-split grid ----------------
__global__ __launch_bounds__(256) void k_gemm_node(const u16* __restrict__ aggr, const u16* __restrict__ hin,
    const u16* __restrict__ Bs, const float* __restrict__ bias, u16* __restrict__ out){
    __shared__ __align__(16) u16 ldsB[4096];   // 8 KB: one k32-chunk, 8 local ntiles
    int t = threadIdx.x, wave = t >> 6, lane = t & 63;
    int m0 = blockIdx.x * 64 + wave * 16;
    int nb = blockIdx.y * 8;                   // global ntile base (8 ntiles = 128 cols)
    int ml = lane & 15, g = lane >> 4;
    int arow = m0 + ml; if (arow > NN - 1) arow = NN - 1;
    const u16* pa = aggr + arow * 256;
    const u16* ph = hin  + arow * 256;

    int flat0 = t * 8, flat1 = (256 + t) * 8;
    int s0i = flat0 >> 9, o0 = flat0 & 511;    // local ntile 0..3
    int s1i = flat1 >> 9, o1 = flat1 & 511;    // local ntile 4..7
    uint4 p0 = *(const uint4*)(Bs + ((nb + s0i) * 16 + 0) * 512 + o0);
    uint4 p1 = *(const uint4*)(Bs + ((nb + s1i) * 16 + 0) * 512 + o1);

    f32x4 acc[8] = {};
    for (int k32 = 0; k32 < 16; k32++){
        __syncthreads();
        *(uint4*)(&ldsB[s0i * 512 + o0]) = p0;
        *(uint4*)(&ldsB[s1i * 512 + o1]) = p1;
        if (k32 < 15){
            p0 = *(const uint4*)(Bs + ((nb + s0i) * 16 + k32 + 1) * 512 + o0);
            p1 = *(const uint4*)(Bs + ((nb + s1i) * 16 + k32 + 1) * 512 + o1);
        }
        __syncthreads();
        const u16* asrc = (k32 < 8) ? (pa + k32 * 32) : (ph + (k32 - 8) * 32);
        bf16x8 af = __builtin_bit_cast(bf16x8, *(const uint4*)(asrc + g * 8));
        #pragma unroll
        for (int nt = 0; nt < 8; nt++){
            bf16x8 bfr = __builtin_bit_cast(bf16x8, *(const uint4*)(&ldsB[(nt * 64 + lane) * 8]));
            acc[nt] = __builtin_amdgcn_mfma_f32_16x16x32_bf16(af, bfr, acc[nt], 0, 0, 0);
        }
    }
    #pragma unroll
    for (int nt = 0; nt < 8; nt++){
        int n = (nb + nt) * 16 + ml;
        float bn = bias[n];
        #pragma unroll
        for (int r = 0; r < 4; r++){
            int rowg = m0 + g * 4 + r;
            if (rowg < NN){
                float v = acc[nt][r] + bn;
                out[rowg * 256 + n] = f2b(v > 0.f ? v : 0.f);
            }
        }
    }
}

// ---------------- node-level P GEMM: P[:, 0:256]=h@W1a (+b1+td*w513 baked), P[:, 256:512]=h@W1b ----------------
__global__ __launch_bounds__(256) void k_gemm_p(const u16* __restrict__ hin,
    const u16* __restrict__ Bc, const float* __restrict__ b1, const float* __restrict__ W1tail,
    const float* __restrict__ tdp, float* __restrict__ P){
    __shared__ __align__(16) u16 ldsB[4096];   // 8 KB: one k32-chunk, 8 local ntiles
    int t = threadIdx.x, wave = t >> 6, lane = t & 63;
    int m0 = blockIdx.x * 64 + wave * 16;
    int nb = blockIdx.y * 8;                   // global ntile base (0..31 total)
    int ml = lane & 15, g = lane >> 4;
    int arow = m0 + ml; if (arow > NN - 1) arow = NN - 1;
    const u16* ph = hin + arow * 256;
    float td = tdp[0];

    int flat0 = t * 8, flat1 = (256 + t) * 8;
    int s0i = flat0 >> 9, o0 = flat0 & 511;
    int s1i = flat1 >> 9, o1 = flat1 & 511;
    uint4 p0 = *(const uint4*)(Bc + ((nb + s0i) * 8 + 0) * 512 + o0);
    uint4 p1 = *(const uint4*)(Bc + ((nb + s1i) * 8 + 0) * 512 + o1);

    f32x4 acc[8] = {};
    for (int k32 = 0; k32 < 8; k32++){
        __syncthreads();
        *(uint4*)(&ldsB[s0i * 512 + o0]) = p0;
        *(uint4*)(&ldsB[s1i * 512 + o1]) = p1;
        if (k32 < 7){
            p0 = *(const uint4*)(Bc + ((nb + s0i) * 8 + k32 + 1) * 512 + o0);
            p1 = *(const uint4*)(Bc + ((nb + s1i) * 8 + k32 + 1) * 512 + o1);
        }
        __syncthreads();
        bf16x8 af = __builtin_bit_cast(bf16x8, *(const uint4*)(ph + k32 * 32 + g * 8));
        #pragma unroll
        for (int nt = 0; nt < 8; nt++){
            bf16x8 bfr = __builtin_bit_cast(bf16x8, *(const uint4*)(&ldsB[(nt * 64 + lane) * 8]));
            acc[nt] = __builtin_amdgcn_mfma_f32_16x16x32_bf16(af, bfr, acc[nt], 0, 0, 0);
        }
    }
    #pragma unroll
    for (int nt = 0; nt < 8; nt++){
        int n = (nb + nt) * 16 + ml;                       // 0..511
        float base = (n < 256) ? (b1[n] + td * W1tail[256 + n]) : 0.f;
        #pragma unroll
        for (int r = 0; r < 4; r++){
            int rowg = m0 + g * 4 + r;
            if (rowg < NN) P[(size_t)rowg * 512 + n] = acc[nt][r] + base;
        }
    }
}

// ---------------- edge kernel (CSR-ordered, latency-optimized) ----------------
// 256 threads / 64 edges per block, 40 KB LDS -> 4 blocks/CU. Phase A: meta int4
// (one broadcast load per edge), 2 edges in flight per 32-lane half. Phase B: GEMM2 + W3 dot.
__global__ __launch_bounds__(256) void k_edge(const float* __restrict__ P,
    const int4* __restrict__ meta, const float* __restrict__ W1tail,
    const u16* __restrict__ B2s, const float* __restrict__ b2v,
    const float* __restrict__ W3, const float* __restrict__ b3, float* __restrict__ out){
    __shared__ __align__(16) u16 ldsX[4096];    // 8 KB: one B2 k32-chunk
    __shared__ __align__(16) u16 ldsZ[16384];   // 32 KB: z1, per-wave 16 x 256, xor-swizzled
    int t = threadIdx.x, wave = t >> 6, lane = t & 63;
    int m0 = blockIdx.x * 64;
    int half = lane >> 5, cl = lane & 31;
    int c0 = cl * 8;

    float wv[8];
    #pragma unroll
    for (int j = 0; j < 8; j++) wv[j] = W1tail[c0 + j];   // w512 chunk, fixed per lane

    // phase A: wave's 16 CSR slots; 2 edges in flight per half (unroll x2)
    #pragma unroll
    for (int it = 0; it < 8; it += 2){
        int rA = it * 2 + half;
        int rB = it * 2 + 2 + half;
        int sA = m0 + wave * 16 + rA; if (sA > NE - 1) sA = NE - 1;
        int sB = m0 + wave * 16 + rB; if (sB > NE - 1) sB = NE - 1;
        int4 mA = meta[sA];
        int4 mB = meta[sB];
        const float* paA = P + (size_t)mA.x * 512;
        const float* pbA = P + (size_t)mA.y * 512 + 256;
        const float* paB = P + (size_t)mB.x * 512;
        const float* pbB = P + (size_t)mB.y * 512 + 256;
        float eA = __builtin_bit_cast(float, mA.w);
        float eB = __builtin_bit_cast(float, mB.w);
        float4 Aa0 = *(const float4*)(paA + c0);
        float4 Aa1 = *(const float4*)(paA + c0 + 4);
        float4 Ab0 = *(const float4*)(pbA + c0);
        float4 Ab1 = *(const float4*)(pbA + c0 + 4);
        float4 Ba0 = *(const float4*)(paB + c0);
        float4 Ba1 = *(const float4*)(paB + c0 + 4);
        float4 Bb0 = *(const float4*)(pbB + c0);
        float4 Bb1 = *(const float4*)(pbB + c0 + 4);
        float v0, v1, v2, v3, v4, v5, v6, v7;
        uint4 st;
        v0 = Aa0.x + Ab0.x + eA * wv[0]; v1 = Aa0.y + Ab0.y + eA * wv[1];
        v2 = Aa0.z + Ab0.z + eA * wv[2]; v3 = Aa0.w + Ab0.w + eA * wv[3];
        v4 = Aa1.x + Ab1.x + eA * wv[4]; v5 = Aa1.y + Ab1.y + eA * wv[5];
        v6 = Aa1.z + Ab1.z + eA * wv[6]; v7 = Aa1.w + Ab1.w + eA * wv[7];
        v0 = v0 > 0.f ? v0 : 0.f; v1 = v1 > 0.f ? v1 : 0.f;
        v2 = v2 > 0.f ? v2 : 0.f; v3 = v3 > 0.f ? v3 : 0.f;
        v4 = v4 > 0.f ? v4 : 0.f; v5 = v5 > 0.f ? v5 : 0.f;
        v6 = v6 > 0.f ? v6 : 0.f; v7 = v7 > 0.f ? v7 : 0.f;
        st.x = (u32)f2b(v0) | ((u32)f2b(v1) << 16);
        st.y = (u32)f2b(v2) | ((u32)f2b(v3) << 16);
        st.z = (u32)f2b(v4) | ((u32)f2b(v5) << 16);
        st.w = (u32)f2b(v6) | ((u32)f2b(v7) << 16);
        *(uint4*)(&ldsZ[wave * 4096 + rA * 256 + ((cl ^ (rA & 7)) << 3)]) = st;
        v0 = Ba0.x + Bb0.x + eB * wv[0]; v1 = Ba0.y + Bb0.y + eB * wv[1];
        v2 = Ba0.z + Bb0.z + eB * wv[2]; v3 = Ba0.w + Bb0.w + eB * wv[3];
        v4 = Ba1.x + Bb1.x + eB * wv[4]; v5 = Ba1.y + Bb1.y + eB * wv[5];
        v6 = Ba1.z + Bb1.z + eB * wv[6]; v7 = Ba1.w + Bb1.w + eB * wv[7];
        v0 = v0 > 0.f ? v0 : 0.f; v1 = v1 > 0.f ? v1 : 0.f;
        v2 = v2 > 0.f ? v2 : 0.f; v3 = v3 > 0.f ? v3 : 0.f;
        v4 = v4 > 0.f ? v4 : 0.f; v5 = v5 > 0.f ? v5 : 0.f;
        v6 = v6 > 0.f ? v6 : 0.f; v7 = v7 > 0.f ? v7 : 0.f;
        st.x = (u32)f2b(v0) | ((u32)f2b(v1) << 16);
        st.y = (u32)f2b(v2) | ((u32)f2b(v3) << 16);
        st.z = (u32)f2b(v4) | ((u32)f2b(v5) << 16);
        st.w = (u32)f2b(v6) | ((u32)f2b(v7) << 16);
        *(uint4*)(&ldsZ[wave * 4096 + rB * 256 + ((cl ^ (rB & 7)) << 3)]) = st;
    }
    // ldsZ is wave-local (each wave reads only its own slice); barriers below cover ldsX

    int ml = lane & 15, g = lane >> 4;
    int nt0 = t >> 6, off0 = (t & 63) * 8;     // thread stages fragments nt0 and nt0+4
    f32x4 acc2[8] = {};
    uint4 q0 = *(const uint4*)(B2s + (nt0 * 8 + 0) * 512 + off0);
    uint4 q1 = *(const uint4*)(B2s + ((nt0 + 4) * 8 + 0) * 512 + off0);
    for (int kc = 0; kc < 8; kc++){
        __syncthreads();
        *(uint4*)(&ldsX[nt0 * 512 + off0]) = q0;
        *(uint4*)(&ldsX[(nt0 + 4) * 512 + off0]) = q1;
        if (kc < 7){
            q0 = *(const uint4*)(B2s + (nt0 * 8 + kc + 1) * 512 + off0);
            q1 = *(const uint4*)(B2s + ((nt0 + 4) * 8 + kc + 1) * 512 + off0);
        }
        __syncthreads();
        int kb = kc * 4 + g;
        bf16x8 af = __builtin_bit_cast(bf16x8, *(const uint4*)(&ldsZ[wave * 4096 + ml * 256 + ((kb ^ (ml & 7)) << 3)]));
        #pragma unroll
        for (int nt = 0; nt < 8; nt++){
            bf16x8 bfr = __builtin_bit_cast(bf16x8, *(const uint4*)(&ldsX[(nt * 64 + lane) * 8]));
            acc2[nt] = __builtin_amdgcn_mfma_f32_16x16x32_bf16(af, bfr, acc2[nt], 0, 0, 0);
        }
    }
    float s0 = 0.f, s1 = 0.f, s2 = 0.f, s3 = 0.f;
    #pragma unroll
    for (int nt = 0; nt < 8; nt++){
        int n = nt * 16 + ml;
        float bn = b2v[n];
        float w3 = W3[n];
        float z;
        z = acc2[nt][0] + bn; s0 += (z > 0.f ? z : 0.f) * w3;
        z = acc2[nt][1] + bn; s1 += (z > 0.f ? z : 0.f) * w3;
        z = acc2[nt][2] + bn; s2 += (z > 0.f ? z : 0.f) * w3;
        z = acc2[nt][3] + bn; s3 += (z > 0.f ? z : 0.f) * w3;
    }
    #pragma unroll
    for (int d = 1; d < 16; d <<= 1){
        s0 += __shfl_xor(s0, d); s1 += __shfl_xor(s1, d);
        s2 += __shfl_xor(s2, d); s3 += __shfl_xor(s3, d);
    }
    if (ml == 0){
        float bb = b3[0];
        int sb = m0 + wave * 16 + g * 4;
        const int* mz = (const int*)meta;
        if (sb + 0 < NE) out[mz[(sb + 0) * 4 + 2]] = s0 + bb;
        if (sb + 1 < NE) out[mz[(sb + 1) * 4 + 2]] = s1 + bb;
        if (sb + 2 < NE) out[mz[(sb + 2) * 4 + 2]] = s2 + bb;
        if (sb + 3 < NE) out[mz[(sb + 3) * 4 + 2]] = s3 + bb;
    }
}

__global__ void k_fillcode_f32(float* __restrict__ out, float c){
    int i = blockIdx.x * 256 + threadIdx.x;
    if (i < NE) out[i] = c;
}

extern "C" void kernel_launch(void* const* d_in, const int* in_sizes, int n_in,
                              void* d_out, int out_size, void* d_ws, size_t ws_size,
                              hipStream_t stream){
    float* out = (float*)d_out;

    static const int exp_sizes[19] = {60000,600000,300000,1,768,256,768,65536,256,65536,
                                      65536,256,65536,131584,256,32768,128,128,1};
    int bad = -1;
    if (n_in != 19) bad = 19;
    else for (int k = 0; k < 19; k++) if (in_sizes[k] != exp_sizes[k]){ bad = k; break; }
    if (bad >= 0){
        k_fillcode_f32<<<(NE + 255) / 256, 256, 0, stream>>>(out, 1000.f + 50.f * bad);
        return;
    }

    char* ws = (char*)d_ws;
    size_t off = 0;
    auto alloc = [&](size_t bytes) -> void* {
        void* p = ws + off;
        off += (bytes + 255) & ~(size_t)255;
        return p;
    };
    int*   deg   = (int*)alloc(NN * 4);
    int*   cur   = (int*)alloc(NN * 4);
    int*   offs  = (int*)alloc((NN + 1) * 4);
    float* invd  = (float*)alloc(NN * 4);
    int*   srcs  = (int*)alloc(NE * 4);
    int4*  meta  = (int4*)alloc((size_t)NE * 16);
    u16*   h1b   = (u16*)alloc((size_t)NN * 256 * 2);
    u16*   h2b   = (u16*)alloc((size_t)NN * 256 * 2);
    u16*   h3b   = (u16*)alloc((size_t)NN * 256 * 2);
    u16*   aggb  = (u16*)alloc((size_t)NN * 256 * 2);
    u16*   WLs2  = (u16*)alloc(512 * 256 * 2);
    u16*   WLs3  = (u16*)alloc(512 * 256 * 2);
    u16*   Bcat  = (u16*)alloc(512 * 256 * 2);          // [W1a|W1b] cat fragments
    u16*   B2s   = (u16*)alloc(256 * 128 * 2);
    float* Pbuf  = (float*)alloc((size_t)NN * 512 * 4); // 41 MB: [Pa|Pb] f32
    if (off > ws_size){
        k_fillcode_f32<<<(NE + 255) / 256, 256, 0, stream>>>(out, 9000.f);
        return;
    }

    const float* x   = (const float*)d_in[0];
    const int*   ei  = (const int*)d_in[1];     // (2,E) int32: [row..., col...]
    const float* ea  = (const float*)d_in[2];
    const float* td  = (const float*)d_in[3];
    const float* Wl1 = (const float*)d_in[4];
    const float* bl1 = (const float*)d_in[5];
    const float* Wr1 = (const float*)d_in[6];
    const float* Wl2 = (const float*)d_in[7];
    const float* bl2 = (const float*)d_in[8];
    const float* Wr2 = (const float*)d_in[9];
    const float* Wl3 = (const float*)d_in[10];
    const float* bl3 = (const float*)d_in[11];
    const float* Wr3 = (const float*)d_in[12];
    const float* W1  = (const float*)d_in[13];
    const float* b1  = (const float*)d_in[14];
    const float* W2  = (const float*)d_in[15];
    const float* b2  = (const float*)d_in[16];
    const float* W3  = (const float*)d_in[17];
    const float* b3  = (const float*)d_in[18];

    hipMemsetAsync(deg, 0, (size_t)((char*)cur - (char*)deg) + NN * 4, stream);

    const int* rowv = ei;          // sources
    const int* colv = ei + NE;     // targets

    k_count<<<(NE + 255) / 256, 256, 0, stream>>>(colv, deg);
    k_scan <<<1, 1024, 0, stream>>>(deg, offs, invd);
    k_fill <<<(NE + 255) / 256, 256, 0, stream>>>(rowv, colv, ea, offs, cur, srcs, meta);

    // weight fragment prep
    k_swz_pair_f32<<<512, 256, 0, stream>>>(Wl2, Wr2, WLs2, 256, 256, 16);
    k_swz_pair_f32<<<512, 256, 0, stream>>>(Wl3, Wr3, WLs3, 256, 256, 16);
    k_swz_cat<<<512, 256, 0, stream>>>(W1, Bcat);
    k_swz_f32<<<128, 256, 0, stream>>>(W2, B2s, 128, 8);

    // SAGE layer 1 (fp32 math, bf16 out)
    k_layer1<<<NN / 4, 256, 0, stream>>>(x, offs, srcs, invd, Wl1, bl1, Wr1, h1b);

    dim3 ggrid((NN + 63) / 64, 2);

    // SAGE layers 2,3: separate aggr (high TLP) + N-split staged GEMM
    k_aggr<<<NN / 4, 256, 0, stream>>>(h1b, offs, srcs, invd, aggb);
    k_gemm_node<<<ggrid, 256, 0, stream>>>(aggb, h1b, WLs2, bl2, h2b);

    k_aggr<<<NN / 4, 256, 0, stream>>>(h2b, offs, srcs, invd, aggb);
    k_gemm_node<<<ggrid, 256, 0, stream>>>(aggb, h2b, WLs3, bl3, h3b);

    // node-level P = h3 @ [W1a|W1b] (f32, bias+td baked into Pa cols)
    dim3 pgrid((NN + 63) / 64, 4);
    k_gemm_p<<<pgrid, 256, 0, stream>>>(h3b, Bcat, b1, W1 + 512 * 256, td, Pbuf);

    // edge kernel (CSR order, 64 edges/block): gather Pa[src]+Pb[col] via meta, relu -> GEMM2 -> W3 dot
    k_edge<<<(NE + 63) / 64, 256, 0, stream>>>(Pbuf, meta, W1 + 512 * 256,
                                               B2s, b2, W3, b3, out);
}

// Round 8
// 321.586 us; speedup vs baseline: 1.3657x; 1.1065x over previous
//
#include <hip/hip_runtime.h>

#define NN 20000
#define NE 300000

typedef unsigned short u16;
typedef unsigned int   u32;

typedef __bf16 bf16x8 __attribute__((ext_vector_type(8)));
typedef float  f32x4  __attribute__((ext_vector_type(4)));

__device__ __forceinline__ float b2f(u16 u){ u32 x = ((u32)u) << 16; return __builtin_bit_cast(float, x); }
__device__ __forceinline__ u16 f2b(float f){
    u32 x = __builtin_bit_cast(u32, f);
    u32 r = x + 0x7fffu + ((x >> 16) & 1u);
    return (u16)(r >> 16);
}

// ---------------- CSR build: bucket edges by col (target) ----------------
__global__ void k_count(const int* __restrict__ key, int* __restrict__ deg){
    int e = blockIdx.x * 256 + threadIdx.x;
    if (e < NE){
        int c = key[e];
        if (c >= 0 && c < NN) atomicAdd(&deg[c], 1);
    }
}

__global__ void k_scan(const int* __restrict__ deg, int* __restrict__ offs, float* __restrict__ invd){
    __shared__ int part[1024];
    int t = threadIdx.x;
    int base = t * 20;
    int s = 0;
    for (int i = 0; i < 20; i++){ int idx = base + i; if (idx < NN) s += deg[idx]; }
    part[t] = s; __syncthreads();
    for (int d = 1; d < 1024; d <<= 1){
        int v = (t >= d) ? part[t - d] : 0;
        __syncthreads();
        part[t] += v;
        __syncthreads();
    }
    int run = part[t] - s;
    for (int i = 0; i < 20; i++){
        int idx = base + i;
        if (idx < NN){
            offs[idx] = run;
            int d0 = deg[idx];
            run += d0;
            invd[idx] = 1.0f / (float)(d0 > 0 ? d0 : 1);
        }
    }
    if (t == 1023) offs[NN] = part[1023];
}

// fills srcs (for layer1/aggr) and meta int4 {src, col, orig edge id, ea bits} (for k_edge)
__global__ void k_fill(const int* __restrict__ val, const int* __restrict__ key,
                       const float* __restrict__ ea, const int* __restrict__ offs,
                       int* __restrict__ cur, int* __restrict__ srcs, int4* __restrict__ meta){
    int e = blockIdx.x * 256 + threadIdx.x;
    if (e < NE){
        int c = key[e];
        if (c >= 0 && c < NN){
            int slot = offs[c] + atomicAdd(&cur[c], 1);
            int r = val[e];
            int sv = (r >= 0 && r < NN) ? r : 0;
            srcs[slot] = sv;
            int4 m;
            m.x = sv;
            m.y = c;
            m.z = e;
            m.w = __builtin_bit_cast(int, ea[e]);
            meta[slot] = m;
        }
    }
}

// ---------------- weight swizzle fp32 -> bf16 MFMA B-fragments ----------------
__global__ void k_swz_f32(const float* __restrict__ W, u16* __restrict__ dst, int N, int KT){
    int t = blockIdx.x * 256 + threadIdx.x;
    int j = t & 7, lane = (t >> 3) & 63, tile = t >> 9;
    int ktile = tile % KT, ntile = tile / KT;
    int k = ktile * 32 + ((lane >> 4) << 3) + j;
    int n = ntile * 16 + (lane & 15);
    dst[t] = f2b(W[k * N + n]);
}

__global__ void k_swz_pair_f32(const float* __restrict__ A, const float* __restrict__ B, u16* __restrict__ dst,
                               int halfK, int N, int KT){
    int t = blockIdx.x * 256 + threadIdx.x;
    int j = t & 7, lane = (t >> 3) & 63, tile = t >> 9;
    int ktile = tile % KT, ntile = tile / KT;
    int k = ktile * 32 + ((lane >> 4) << 3) + j;
    int n = ntile * 16 + (lane & 15);
    dst[t] = f2b((k < halfK) ? A[k * N + n] : B[(k - halfK) * N + n]);
}

// cat-swizzle for node-level P GEMM: B_cat[k][n'] = n'<256 ? W1[k][n'] : W1[256+k][n'-256]
__global__ void k_swz_cat(const float* __restrict__ W1, u16* __restrict__ dst){
    int t = blockIdx.x * 256 + threadIdx.x;       // 512 blocks x 256 = 131072
    int j = t & 7, lane = (t >> 3) & 63, tile = t >> 9;
    int ktile = tile & 7, ntile = tile >> 3;
    int k = ktile * 32 + ((lane >> 4) << 3) + j;  // 0..255
    int n = ntile * 16 + (lane & 15);             // 0..511
    float v = (n < 256) ? W1[k * 256 + n] : W1[(256 + k) * 256 + (n - 256)];
    dst[t] = f2b(v);
}

// ---------------- SAGE layer 1 (din=3): fp32 math, bf16 output ----------------
__global__ void k_layer1(const float* __restrict__ x, const int* __restrict__ offs, const int* __restrict__ srcs,
                         const float* __restrict__ invd, const float* __restrict__ Wl, const float* __restrict__ bl,
                         const float* __restrict__ Wr, u16* __restrict__ h1){
    int node = blockIdx.x * 4 + (threadIdx.x >> 6);
    int lane = threadIdx.x & 63;
    int st = offs[node], en = offs[node + 1];
    float s0 = 0.f, s1 = 0.f, s2 = 0.f;
    for (int j = st + lane; j < en; j += 64){
        int s = srcs[j];
        s0 += x[s * 3 + 0]; s1 += x[s * 3 + 1]; s2 += x[s * 3 + 2];
    }
    #pragma unroll
    for (int d = 1; d < 64; d <<= 1){
        s0 += __shfl_xor(s0, d); s1 += __shfl_xor(s1, d); s2 += __shfl_xor(s2, d);
    }
    float inv = invd[node];
    float a0 = s0 * inv, a1 = s1 * inv, a2 = s2 * inv;
    float xi0 = x[node * 3 + 0], xi1 = x[node * 3 + 1], xi2 = x[node * 3 + 2];
    int f0 = lane * 4;
    ushort4 stv;
    u16* sp = (u16*)&stv;
    #pragma unroll
    for (int r = 0; r < 4; r++){
        int n = f0 + r;
        float o = a0 * Wl[n] + a1 * Wl[256 + n] + a2 * Wl[512 + n]
                + xi0 * Wr[n] + xi1 * Wr[256 + n] + xi2 * Wr[512 + n] + bl[n];
        sp[r] = f2b(o > 0.f ? o : 0.f);
    }
    *(ushort4*)(h1 + node * 256 + f0) = stv;
}

// ---------------- mean aggregation over CSR: 4 rows in flight per wave (16 lanes x 16 bf16 each) ----------------
__global__ void k_aggr(const u16* __restrict__ hin, const int* __restrict__ offs, const int* __restrict__ srcs,
                       const float* __restrict__ invd, u16* __restrict__ aggr){
    int node = blockIdx.x * 4 + (threadIdx.x >> 6);
    int lane = threadIdx.x & 63;
    int st = offs[node], en = offs[node + 1];
    int q = lane >> 4;            // 0..3: row-group (4 edges in flight)
    int c0 = (lane & 15) * 16;    // u16 units: 16 bf16 per lane
    float a[16];
    #pragma unroll
    for (int i = 0; i < 16; i++) a[i] = 0.f;
    for (int j = st + q; j < en; j += 4){
        int s = srcs[j];
        const u16* hp = hin + s * 256 + c0;
        uint4 v0 = *(const uint4*)(hp);
        uint4 v1 = *(const uint4*)(hp + 8);
        a[0]  += b2f((u16)v0.x); a[1]  += b2f((u16)(v0.x >> 16));
        a[2]  += b2f((u16)v0.y); a[3]  += b2f((u16)(v0.y >> 16));
        a[4]  += b2f((u16)v0.z); a[5]  += b2f((u16)(v0.z >> 16));
        a[6]  += b2f((u16)v0.w); a[7]  += b2f((u16)(v0.w >> 16));
        a[8]  += b2f((u16)v1.x); a[9]  += b2f((u16)(v1.x >> 16));
        a[10] += b2f((u16)v1.y); a[11] += b2f((u16)(v1.y >> 16));
        a[12] += b2f((u16)v1.z); a[13] += b2f((u16)(v1.z >> 16));
        a[14] += b2f((u16)v1.w); a[15] += b2f((u16)(v1.w >> 16));
    }
    #pragma unroll
    for (int i = 0; i < 16; i++){
        a[i] += __shfl_xor(a[i], 16);
        a[i] += __shfl_xor(a[i], 32);
    }
    if (q == 0){
        float inv = invd[node];
        uint4 o0, o1;
        o0.x = (u32)f2b(a[0]  * inv) | ((u32)f2b(a[1]  * inv) << 16);
        o0.y = (u32)f2b(a[2]  * inv) | ((u32)f2b(a[3]  * inv) << 16);
        o0.z = (u32)f2b(a[4]  * inv) | ((u32)f2b(a[5]  * inv) << 16);
        o0.w = (u32)f2b(a[6]  * inv) | ((u32)f2b(a[7]  * inv) << 16);
        o1.x = (u32)f2b(a[8]  * inv) | ((u32)f2b(a[9]  * inv) << 16);
        o1.y = (u32)f2b(a[10] * inv) | ((u32)f2b(a[11] * inv) << 16);
        o1.z = (u32)f2b(a[12] * inv) | ((u32)f2b(a[13] * inv) << 16);
        o1.w = (u32)f2b(a[14] * inv) | ((u32)f2b(a[15] * inv) << 16);
        *(uint4*)(aggr + node * 256 + c0) = o0;
        *(uint4*)(aggr + node * 256 + c0 + 8) = o1;
    }
}

// ---------------- node dense layer: relu([aggr|hin] @ Bs + bias), MFMA, N-split grid ----------------
__global__ __launch_bounds__(256) void k_gemm_node(const u16* __restrict__ aggr, const u16* __restrict__ hin,
    const u16* __restrict__ Bs, const float* __restrict__ bias, u16* __restrict__ out){
    __shared__ __align__(16) u16 ldsB[4096];   // 8 KB: one k32-chunk, 8 local ntiles
    int t = threadIdx.x, wave = t >> 6, lane = t & 63;
    int m0 = blockIdx.x * 64 + wave * 16;
    int nb = blockIdx.y * 8;                   // global ntile base (8 ntiles = 128 cols)
    int ml = lane & 15, g = lane >> 4;
    int arow = m0 + ml; if (arow > NN - 1) arow = NN - 1;
    const u16* pa = aggr + arow * 256;
    const u16* ph = hin  + arow * 256;

    int flat0 = t * 8, flat1 = (256 + t) * 8;
    int s0i = flat0 >> 9, o0 = flat0 & 511;    // local ntile 0..3
    int s1i = flat1 >> 9, o1 = flat1 & 511;    // local ntile 4..7
    uint4 p0 = *(const uint4*)(Bs + ((nb + s0i) * 16 + 0) * 512 + o0);
    uint4 p1 = *(const uint4*)(Bs + ((nb + s1i) * 16 + 0) * 512 + o1);

    f32x4 acc[8] = {};
    for (int k32 = 0; k32 < 16; k32++){
        __syncthreads();
        *(uint4*)(&ldsB[s0i * 512 + o0]) = p0;
        *(uint4*)(&ldsB[s1i * 512 + o1]) = p1;
        if (k32 < 15){
            p0 = *(const uint4*)(Bs + ((nb + s0i) * 16 + k32 + 1) * 512 + o0);
            p1 = *(const uint4*)(Bs + ((nb + s1i) * 16 + k32 + 1) * 512 + o1);
        }
        __syncthreads();
        const u16* asrc = (k32 < 8) ? (pa + k32 * 32) : (ph + (k32 - 8) * 32);
        bf16x8 af = __builtin_bit_cast(bf16x8, *(const uint4*)(asrc + g * 8));
        #pragma unroll
        for (int nt = 0; nt < 8; nt++){
            bf16x8 bfr = __builtin_bit_cast(bf16x8, *(const uint4*)(&ldsB[(nt * 64 + lane) * 8]));
            acc[nt] = __builtin_amdgcn_mfma_f32_16x16x32_bf16(af, bfr, acc[nt], 0, 0, 0);
        }
    }
    #pragma unroll
    for (int nt = 0; nt < 8; nt++){
        int n = (nb + nt) * 16 + ml;
        float bn = bias[n];
        #pragma unroll
        for (int r = 0; r < 4; r++){
            int rowg = m0 + g * 4 + r;
            if (rowg < NN){
                float v = acc[nt][r] + bn;
                out[rowg * 256 + n] = f2b(v > 0.f ? v : 0.f);
            }
        }
    }
}

// ---------------- node-level P GEMM: P = bf16( h@[W1a|W1b] + base ), base = b1 + td*w513 on Pa cols ----------------
__global__ __launch_bounds__(256) void k_gemm_p(const u16* __restrict__ hin,
    const u16* __restrict__ Bc, const float* __restrict__ b1, const float* __restrict__ W1tail,
    const float* __restrict__ tdp, u16* __restrict__ P){
    __shared__ __align__(16) u16 ldsB[4096];   // 8 KB: one k32-chunk, 8 local ntiles
    int t = threadIdx.x, wave = t >> 6, lane = t & 63;
    int m0 = blockIdx.x * 64 + wave * 16;
    int nb = blockIdx.y * 8;                   // global ntile base (0..31 total)
    int ml = lane & 15, g = lane >> 4;
    int arow = m0 + ml; if (arow > NN - 1) arow = NN - 1;
    const u16* ph = hin + arow * 256;
    float td = tdp[0];

    int flat0 = t * 8, flat1 = (256 + t) * 8;
    int s0i = flat0 >> 9, o0 = flat0 & 511;
    int s1i = flat1 >> 9, o1 = flat1 & 511;
    uint4 p0 = *(const uint4*)(Bc + ((nb + s0i) * 8 + 0) * 512 + o0);
    uint4 p1 = *(const uint4*)(Bc + ((nb + s1i) * 8 + 0) * 512 + o1);

    f32x4 acc[8] = {};
    for (int k32 = 0; k32 < 8; k32++){
        __syncthreads();
        *(uint4*)(&ldsB[s0i * 512 + o0]) = p0;
        *(uint4*)(&ldsB[s1i * 512 + o1]) = p1;
        if (k32 < 7){
            p0 = *(const uint4*)(Bc + ((nb + s0i) * 8 + k32 + 1) * 512 + o0);
            p1 = *(const uint4*)(Bc + ((nb + s1i) * 8 + k32 + 1) * 512 + o1);
        }
        __syncthreads();
        bf16x8 af = __builtin_bit_cast(bf16x8, *(const uint4*)(ph + k32 * 32 + g * 8));
        #pragma unroll
        for (int nt = 0; nt < 8; nt++){
            bf16x8 bfr = __builtin_bit_cast(bf16x8, *(const uint4*)(&ldsB[(nt * 64 + lane) * 8]));
            acc[nt] = __builtin_amdgcn_mfma_f32_16x16x32_bf16(af, bfr, acc[nt], 0, 0, 0);
        }
    }
    #pragma unroll
    for (int nt = 0; nt < 8; nt++){
        int n = (nb + nt) * 16 + ml;                       // 0..511
        float base = (n < 256) ? (b1[n] + td * W1tail[256 + n]) : 0.f;
        #pragma unroll
        for (int r = 0; r < 4; r++){
            int rowg = m0 + g * 4 + r;
            if (rowg < NN) P[(size_t)rowg * 512 + n] = f2b(acc[nt][r] + base);
        }
    }
}

// ---------------- edge kernel (CSR-ordered, bf16 P): z1 = relu(Pa[src]+Pb[col]+ea*w512) -> GEMM2 -> W3 dot ----------------
// 256 threads / 64 edges per block, 40 KB LDS -> 4 blocks/CU. bf16 P rows: 512 B each (half the gather bytes).
__global__ __launch_bounds__(256) void k_edge(const u16* __restrict__ P,
    const int4* __restrict__ meta, const float* __restrict__ W1tail,
    const u16* __restrict__ B2s, const float* __restrict__ b2v,
    const float* __restrict__ W3, const float* __restrict__ b3, float* __restrict__ out){
    __shared__ __align__(16) u16 ldsX[4096];    // 8 KB: one B2 k32-chunk
    __shared__ __align__(16) u16 ldsZ[16384];   // 32 KB: z1, per-wave 16 x 256, xor-swizzled
    int t = threadIdx.x, wave = t >> 6, lane = t & 63;
    int m0 = blockIdx.x * 64;
    int half = lane >> 5, cl = lane & 31;
    int c0 = cl * 8;                            // u16 units: 8 bf16 per lane, 32 lanes = 256 dims

    float wv[8];
    #pragma unroll
    for (int j = 0; j < 8; j++) wv[j] = W1tail[c0 + j];   // w512 chunk, fixed per lane

    // phase A: wave's 16 CSR slots; 2 edges in flight per half (unroll x2)
    #pragma unroll
    for (int it = 0; it < 8; it += 2){
        int rA = it * 2 + half;
        int rB = it * 2 + 2 + half;
        int sA = m0 + wave * 16 + rA; if (sA > NE - 1) sA = NE - 1;
        int sB = m0 + wave * 16 + rB; if (sB > NE - 1) sB = NE - 1;
        int4 mA = meta[sA];
        int4 mB = meta[sB];
        const u16* paA = P + (size_t)mA.x * 512;
        const u16* pbA = P + (size_t)mA.y * 512 + 256;
        const u16* paB = P + (size_t)mB.x * 512;
        const u16* pbB = P + (size_t)mB.y * 512 + 256;
        float eA = __builtin_bit_cast(float, mA.w);
        float eB = __builtin_bit_cast(float, mB.w);
        uint4 vaA = *(const uint4*)(paA + c0);
        uint4 vbA = *(const uint4*)(pbA + c0);
        uint4 vaB = *(const uint4*)(paB + c0);
        uint4 vbB = *(const uint4*)(pbB + c0);
        float v0, v1, v2, v3, v4, v5, v6, v7;
        uint4 st;
        v0 = b2f((u16)vaA.x) + b2f((u16)vbA.x) + eA * wv[0];
        v1 = b2f((u16)(vaA.x >> 16)) + b2f((u16)(vbA.x >> 16)) + eA * wv[1];
        v2 = b2f((u16)vaA.y) + b2f((u16)vbA.y) + eA * wv[2];
        v3 = b2f((u16)(vaA.y >> 16)) + b2f((u16)(vbA.y >> 16)) + eA * wv[3];
        v4 = b2f((u16)vaA.z) + b2f((u16)vbA.z) + eA * wv[4];
        v5 = b2f((u16)(vaA.z >> 16)) + b2f((u16)(vbA.z >> 16)) + eA * wv[5];
        v6 = b2f((u16)vaA.w) + b2f((u16)vbA.w) + eA * wv[6];
        v7 = b2f((u16)(vaA.w >> 16)) + b2f((u16)(vbA.w >> 16)) + eA * wv[7];
        v0 = v0 > 0.f ? v0 : 0.f; v1 = v1 > 0.f ? v1 : 0.f;
        v2 = v2 > 0.f ? v2 : 0.f; v3 = v3 > 0.f ? v3 : 0.f;
        v4 = v4 > 0.f ? v4 : 0.f; v5 = v5 > 0.f ? v5 : 0.f;
        v6 = v6 > 0.f ? v6 : 0.f; v7 = v7 > 0.f ? v7 : 0.f;
        st.x = (u32)f2b(v0) | ((u32)f2b(v1) << 16);
        st.y = (u32)f2b(v2) | ((u32)f2b(v3) << 16);
        st.z = (u32)f2b(v4) | ((u32)f2b(v5) << 16);
        st.w = (u32)f2b(v6) | ((u32)f2b(v7) << 16);
        *(uint4*)(&ldsZ[wave * 4096 + rA * 256 + ((cl ^ (rA & 7)) << 3)]) = st;
        v0 = b2f((u16)vaB.x) + b2f((u16)vbB.x) + eB * wv[0];
        v1 = b2f((u16)(vaB.x >> 16)) + b2f((u16)(vbB.x >> 16)) + eB * wv[1];
        v2 = b2f((u16)vaB.y) + b2f((u16)vbB.y) + eB * wv[2];
        v3 = b2f((u16)(vaB.y >> 16)) + b2f((u16)(vbB.y >> 16)) + eB * wv[3];
        v4 = b2f((u16)vaB.z) + b2f((u16)vbB.z) + eB * wv[4];
        v5 = b2f((u16)(vaB.z >> 16)) + b2f((u16)(vbB.z >> 16)) + eB * wv[5];
        v6 = b2f((u16)vaB.w) + b2f((u16)vbB.w) + eB * wv[6];
        v7 = b2f((u16)(vaB.w >> 16)) + b2f((u16)(vbB.w >> 16)) + eB * wv[7];
        v0 = v0 > 0.f ? v0 : 0.f; v1 = v1 > 0.f ? v1 : 0.f;
        v2 = v2 > 0.f ? v2 : 0.f; v3 = v3 > 0.f ? v3 : 0.f;
        v4 = v4 > 0.f ? v4 : 0.f; v5 = v5 > 0.f ? v5 : 0.f;
        v6 = v6 > 0.f ? v6 : 0.f; v7 = v7 > 0.f ? v7 : 0.f;
        st.x = (u32)f2b(v0) | ((u32)f2b(v1) << 16);
        st.y = (u32)f2b(v2) | ((u32)f2b(v3) << 16);
        st.z = (u32)f2b(v4) | ((u32)f2b(v5) << 16);
        st.w = (u32)f2b(v6) | ((u32)f2b(v7) << 16);
        *(uint4*)(&ldsZ[wave * 4096 + rB * 256 + ((cl ^ (rB & 7)) << 3)]) = st;
    }
    // ldsZ is wave-local (each wave reads only its own slice); barriers below cover ldsX

    int ml = lane & 15, g = lane >> 4;
    int nt0 = t >> 6, off0 = (t & 63) * 8;     // thread stages fragments nt0 and nt0+4
    f32x4 acc2[8] = {};
    uint4 q0 = *(const uint4*)(B2s + (nt0 * 8 + 0) * 512 + off0);
    uint4 q1 = *(const uint4*)(B2s + ((nt0 + 4) * 8 + 0) * 512 + off0);
    for (int kc = 0; kc < 8; kc++){
        __syncthreads();
        *(uint4*)(&ldsX[nt0 * 512 + off0]) = q0;
        *(uint4*)(&ldsX[(nt0 + 4) * 512 + off0]) = q1;
        if (kc < 7){
            q0 = *(const uint4*)(B2s + (nt0 * 8 + kc + 1) * 512 + off0);
            q1 = *(const uint4*)(B2s + ((nt0 + 4) * 8 + kc + 1) * 512 + off0);
        }
        __syncthreads();
        int kb = kc * 4 + g;
        bf16x8 af = __builtin_bit_cast(bf16x8, *(const uint4*)(&ldsZ[wave * 4096 + ml * 256 + ((kb ^ (ml & 7)) << 3)]));
        #pragma unroll
        for (int nt = 0; nt < 8; nt++){
            bf16x8 bfr = __builtin_bit_cast(bf16x8, *(const uint4*)(&ldsX[(nt * 64 + lane) * 8]));
            acc2[nt] = __builtin_amdgcn_mfma_f32_16x16x32_bf16(af, bfr, acc2[nt], 0, 0, 0);
        }
    }
    float s0 = 0.f, s1 = 0.f, s2 = 0.f, s3 = 0.f;
    #pragma unroll
    for (int nt = 0; nt < 8; nt++){
        int n = nt * 16 + ml;
        float bn = b2v[n];
        float w3 = W3[n];
        float z;
        z = acc2[nt][0] + bn; s0 += (z > 0.f ? z : 0.f) * w3;
        z = acc2[nt][1] + bn; s1 += (z > 0.f ? z : 0.f) * w3;
        z = acc2[nt][2] + bn; s2 += (z > 0.f ? z : 0.f) * w3;
        z = acc2[nt][3] + bn; s3 += (z > 0.f ? z : 0.f) * w3;
    }
    #pragma unroll
    for (int d = 1; d < 16; d <<= 1){
        s0 += __shfl_xor(s0, d); s1 += __shfl_xor(s1, d);
        s2 += __shfl_xor(s2, d); s3 += __shfl_xor(s3, d);
    }
    if (ml == 0){
        float bb = b3[0];
        int sb = m0 + wave * 16 + g * 4;
        const int* mz = (const int*)meta;
        if (sb + 0 < NE) out[mz[(sb + 0) * 4 + 2]] = s0 + bb;
        if (sb + 1 < NE) out[mz[(sb + 1) * 4 + 2]] = s1 + bb;
        if (sb + 2 < NE) out[mz[(sb + 2) * 4 + 2]] = s2 + bb;
        if (sb + 3 < NE) out[mz[(sb + 3) * 4 + 2]] = s3 + bb;
    }
}

__global__ void k_fillcode_f32(float* __restrict__ out, float c){
    int i = blockIdx.x * 256 + threadIdx.x;
    if (i < NE) out[i] = c;
}

extern "C" void kernel_launch(void* const* d_in, const int* in_sizes, int n_in,
                              void* d_out, int out_size, void* d_ws, size_t ws_size,
                              hipStream_t stream){
    float* out = (float*)d_out;

    static const int exp_sizes[19] = {60000,600000,300000,1,768,256,768,65536,256,65536,
                                      65536,256,65536,131584,256,32768,128,128,1};
    int bad = -1;
    if (n_in != 19) bad = 19;
    else for (int k = 0; k < 19; k++) if (in_sizes[k] != exp_sizes[k]){ bad = k; break; }
    if (bad >= 0){
        k_fillcode_f32<<<(NE + 255) / 256, 256, 0, stream>>>(out, 1000.f + 50.f * bad);
        return;
    }

    char* ws = (char*)d_ws;
    size_t off = 0;
    auto alloc = [&](size_t bytes) -> void* {
        void* p = ws + off;
        off += (bytes + 255) & ~(size_t)255;
        return p;
    };
    int*   deg   = (int*)alloc(NN * 4);
    int*   cur   = (int*)alloc(NN * 4);
    int*   offs  = (int*)alloc((NN + 1) * 4);
    float* invd  = (float*)alloc(NN * 4);
    int*   srcs  = (int*)alloc(NE * 4);
    int4*  meta  = (int4*)alloc((size_t)NE * 16);
    u16*   h1b   = (u16*)alloc((size_t)NN * 256 * 2);
    u16*   h2b   = (u16*)alloc((size_t)NN * 256 * 2);
    u16*   h3b   = (u16*)alloc((size_t)NN * 256 * 2);
    u16*   aggb  = (u16*)alloc((size_t)NN * 256 * 2);
    u16*   WLs2  = (u16*)alloc(512 * 256 * 2);
    u16*   WLs3  = (u16*)alloc(512 * 256 * 2);
    u16*   Bcat  = (u16*)alloc(512 * 256 * 2);          // [W1a|W1b] cat fragments
    u16*   B2s   = (u16*)alloc(256 * 128 * 2);
    u16*   Pbuf  = (u16*)alloc((size_t)NN * 512 * 2);   // 20.5 MB: [Pa|Pb] bf16
    if (off > ws_size){
        k_fillcode_f32<<<(NE + 255) / 256, 256, 0, stream>>>(out, 9000.f);
        return;
    }

    const float* x   = (const float*)d_in[0];
    const int*   ei  = (const int*)d_in[1];     // (2,E) int32: [row..., col...]
    const float* ea  = (const float*)d_in[2];
    const float* td  = (const float*)d_in[3];
    const float* Wl1 = (const float*)d_in[4];
    const float* bl1 = (const float*)d_in[5];
    const float* Wr1 = (const float*)d_in[6];
    const float* Wl2 = (const float*)d_in[7];
    const float* bl2 = (const float*)d_in[8];
    const float* Wr2 = (const float*)d_in[9];
    const float* Wl3 = (const float*)d_in[10];
    const float* bl3 = (const float*)d_in[11];
    const float* Wr3 = (const float*)d_in[12];
    const float* W1  = (const float*)d_in[13];
    const float* b1  = (const float*)d_in[14];
    const float* W2  = (const float*)d_in[15];
    const float* b2  = (const float*)d_in[16];
    const float* W3  = (const float*)d_in[17];
    const float* b3  = (const float*)d_in[18];

    hipMemsetAsync(deg, 0, (size_t)((char*)cur - (char*)deg) + NN * 4, stream);

    const int* rowv = ei;          // sources
    const int* colv = ei + NE;     // targets

    k_count<<<(NE + 255) / 256, 256, 0, stream>>>(colv, deg);
    k_scan <<<1, 1024, 0, stream>>>(deg, offs, invd);
    k_fill <<<(NE + 255) / 256, 256, 0, stream>>>(rowv, colv, ea, offs, cur, srcs, meta);

    // weight fragment prep
    k_swz_pair_f32<<<512, 256, 0, stream>>>(Wl2, Wr2, WLs2, 256, 256, 16);
    k_swz_pair_f32<<<512, 256, 0, stream>>>(Wl3, Wr3, WLs3, 256, 256, 16);
    k_swz_cat<<<512, 256, 0, stream>>>(W1, Bcat);
    k_swz_f32<<<128, 256, 0, stream>>>(W2, B2s, 128, 8);

    // SAGE layer 1 (fp32 math, bf16 out)
    k_layer1<<<NN / 4, 256, 0, stream>>>(x, offs, srcs, invd, Wl1, bl1, Wr1, h1b);

    dim3 ggrid((NN + 63) / 64, 2);

    // SAGE layers 2,3: separate aggr (high TLP, 4 rows in flight) + N-split staged GEMM
    k_aggr<<<NN / 4, 256, 0, stream>>>(h1b, offs, srcs, invd, aggb);
    k_gemm_node<<<ggrid, 256, 0, stream>>>(aggb, h1b, WLs2, bl2, h2b);

    k_aggr<<<NN / 4, 256, 0, stream>>>(h2b, offs, srcs, invd, aggb);
    k_gemm_node<<<ggrid, 256, 0, stream>>>(aggb, h2b, WLs3, bl3, h3b);

    // node-level P = bf16(h3 @ [W1a|W1b] + base)
    dim3 pgrid((NN + 63) / 64, 4);
    k_gemm_p<<<pgrid, 256, 0, stream>>>(h3b, Bcat, b1, W1 + 512 * 256, td, Pbuf);

    // edge kernel (CSR order, 64 edges/block, bf16 P): gather Pa[src]+Pb[col], relu -> GEMM2 -> W3 dot
    k_edge<<<(NE + 63) / 64, 256, 0, stream>>>(Pbuf, meta, W1 + 512 * 256,
                                               B2s, b2, W3, b3, out);
}